// Round 3
// baseline (234.045 us; speedup 1.0000x reference)
//
#include <hip/hip_runtime.h>
#include <math.h>

// MatchingLayer (BiMPM-style) — MI355X. Round 3: 3-dispatch fused pipeline.
// B=32, L=128, H=100, P=20, C=105.

namespace {
constexpr int B = 32;
constexpr int L = 128;
constexpr int H = 100;
constexpr int P = 20;
constexpr int C = 105;
constexpr float EPSF = 1e-8f;
constexpr float MINV = -1e7f;
}

typedef unsigned short u16;
typedef unsigned int u32;
typedef short sh8 __attribute__((ext_vector_type(8)));   // 8 bf16 (4 VGPRs)
typedef float f4 __attribute__((ext_vector_type(4)));

__device__ __forceinline__ u16 f2bf(float f) {           // RNE f32->bf16
    u32 u = __float_as_uint(f);
    u += 0x7FFFu + ((u >> 16) & 1u);
    return (u16)(u >> 16);
}
__device__ __forceinline__ float bf2f(u32 h) {
    return __uint_as_float(h << 16);
}

// ---------------------------------------------------------------- k_prep
// grid (L,B,2), block 128. Masked vector (fp32 + bf16 K=128 padded copy),
// plain norm, P w1-weighted norms. side=z picks p/h.
__global__ void k_prep(const float* __restrict__ ctx_p, const int* __restrict__ mask_p,
                       const float* __restrict__ ctx_h, const int* __restrict__ mask_h,
                       const float* __restrict__ w1,
                       float* __restrict__ cp, float* __restrict__ ch,
                       u16* __restrict__ cpb, u16* __restrict__ chb,
                       float* __restrict__ np_, float* __restrict__ nh_,
                       float* __restrict__ nwp, float* __restrict__ nwh)
{
    const int b = blockIdx.y, i = blockIdx.x, side = blockIdx.z, t = threadIdx.x;
    const float* ctx = side ? ctx_h : ctx_p;
    const int*  mask = side ? mask_h : mask_p;
    float* dst  = side ? ch  : cp;
    u16*   dstb = side ? chb : cpb;
    float* nrm  = side ? nh_ : np_;
    float* nw   = side ? nwh : nwp;

    const int row = b * L + i;
    __shared__ __align__(16) float sv2[H];
    const float m = (float)mask[row];
    float v = 0.f;
    if (t < H) {
        v = ctx[row * H + t] * m;
        dst[row * H + t] = v;
        sv2[t] = v * v;
    }
    dstb[row * 128 + t] = f2bf(v);   // zero pad for t>=H
    __syncthreads();
    if (t < P) {
        const float4* w4 = (const float4*)(w1 + t * H);
        const float4* v4 = (const float4*)sv2;
        float acc = 0.f;
        #pragma unroll
        for (int k = 0; k < H / 4; ++k) {
            float4 w = w4[k], s = v4[k];
            acc += w.x * w.x * s.x + w.y * w.y * s.y + w.z * w.z * s.z + w.w * w.w * s.w;
        }
        nw[row * P + t] = sqrtf(acc);
    } else if (t == P) {
        const float4* v4 = (const float4*)sv2;
        float acc = 0.f;
        #pragma unroll
        for (int k = 0; k < H / 4; ++k) {
            float4 s = v4[k];
            acc += s.x + s.y + s.z + s.w;
        }
        nrm[row] = sqrtf(acc);
    }
}

// ---------------------------------------------------------------- k_side
// grid (L,B,2), block 256. Per (b,i,side): stage Bv b-slice in LDS, compute
// cos row locally (h-side == transposed column by symmetry), last-B vector,
// attentive mean/max, all cosine-sim epilogues. No cosM materialization.
__global__ __launch_bounds__(256) void
k_side(const float* __restrict__ cp, const float* __restrict__ ch,
       const float* __restrict__ np_, const float* __restrict__ nh_,
       const int* __restrict__ mask_p, const int* __restrict__ mask_h,
       const float* __restrict__ w0, const float* __restrict__ w2,
       const float* __restrict__ w3, float* __restrict__ out)
{
    const int b = blockIdx.y, i = blockIdx.x, side = blockIdx.z, t = threadIdx.x;
    const float* A   = side ? ch : cp;
    const float* Bv  = side ? cp : ch;
    const float* nA_ = side ? nh_ : np_;
    const float* nB_ = side ? np_ : nh_;
    const int* maskA = side ? mask_h : mask_p;
    const int* maskB = side ? mask_p : mask_h;
    float* orow = out + ((size_t)side * B * L + (size_t)b * L + i) * C;

    __shared__ __align__(16) float sBv[L * H];           // 51.2 KB
    __shared__ __align__(16) float sa[H], sl[H], sam[H], sax[H];
    __shared__ float scos[L], smb[L], snB[L];
    __shared__ float pam[2][H], pax[2][H];
    __shared__ float s_scal[4];   // sumcos, mmax, cosmax, cosmean

    const float mA = (float)maskA[b * L + i];
    const float nAi = nA_[b * L + i];
    if (t < H) sa[t] = A[(b * L + i) * H + t];
    if (t < L) {
        smb[t] = mA * (float)maskB[b * L + t];
        snB[t] = nB_[b * L + t];
    }
    {   // stage Bv b-slice (coalesced float4, linear map)
        const float4* g4 = (const float4*)(Bv + (size_t)b * L * H);
        float4* s4 = (float4*)sBv;
        #pragma unroll
        for (int r = 0; r < 13; ++r) {
            int idx = r * 256 + t;
            if (idx < L * H / 4) s4[idx] = g4[idx];
        }
    }
    __syncthreads();

    if (t < L) {   // waves 0-1: local cos row
        const float4* a4 = (const float4*)sa;
        const float4* b4 = (const float4*)(sBv + t * H);
        float dot = 0.f;
        #pragma unroll
        for (int k = 0; k < H / 4; ++k) {
            float4 a = a4[k], v = b4[k];
            dot += a.x * v.x + a.y * v.y + a.z * v.z + a.w * v.w;
        }
        scos[t] = dot / fmaxf(nAi * snB[t], EPSF);
    } else {       // waves 2-3: last-index of B side + load last vector
        const int tt = t - 128;
        const int l = tt & 63;
        float s0 = (float)maskB[b * L + l] + (float)maskB[b * L + l + 64];
        for (int d = 1; d < 64; d <<= 1) s0 += __shfl_xor(s0, d);
        int idx = (int)s0 - 1; if (idx < 0) idx = 0;
        if (tt < H) sl[tt] = Bv[(b * L + idx) * H + tt];
    }
    __syncthreads();

    if (t < 64) {  // wave0: block-wide scalars
        float c0 = scos[t], c1 = scos[t + 64];
        float b0 = smb[t], b1 = smb[t + 64];
        float sc = c0 + c1;
        float sm = c0 * b0 + c1 * b1;
        float cn = b0 + b1;
        float mm = fmaxf(b0, b1);
        float vm = fmaxf(b0 > 0.f ? c0 : MINV, b1 > 0.f ? c1 : MINV);
        for (int d = 1; d < 64; d <<= 1) {
            sc += __shfl_xor(sc, d);
            sm += __shfl_xor(sm, d);
            cn += __shfl_xor(cn, d);
            mm = fmaxf(mm, __shfl_xor(mm, d));
            vm = fmaxf(vm, __shfl_xor(vm, d));
        }
        if (t == 0) {
            s_scal[0] = sc; s_scal[1] = mm;
            s_scal[2] = vm * mm;
            s_scal[3] = sm / fmaxf(cn, EPSF);
        }
    }
    {   // attentive partials from LDS: group g covers j in [g*64, g*64+64)
        const int g = t >> 7, tt = t & 127;
        if (tt < H) {
            float am = 0.f, ax = MINV;
            const int j0 = g * 64;
            for (int j = j0; j < j0 + 64; ++j) {
                float v = scos[j] * sBv[j * H + tt];
                am += v;
                ax = fmaxf(ax, smb[j] > 0.f ? v : MINV);
            }
            pam[g][tt] = am; pax[g][tt] = ax;
        }
    }
    __syncthreads();
    if (t < H) {
        sam[t] = (pam[0][t] + pam[1][t]) / fmaxf(s_scal[0], EPSF);
        sax[t] = fmaxf(pax[0][t], pax[1][t]) * s_scal[1];
    }
    __syncthreads();

    const int wv = t >> 6, ln = t & 63;
    if (wv < 3) {
        if (ln < P) {
            const float* wmat = (wv == 0) ? w0 : (wv == 1) ? w2 : w3;
            const float* oth  = (wv == 0) ? sl : (wv == 1) ? sam : sax;
            const float4* w4 = (const float4*)(wmat + ln * H);
            const float4* a4 = (const float4*)sa;
            const float4* o4 = (const float4*)oth;
            float d = 0.f, na = 0.f, nb = 0.f;
            #pragma unroll 5
            for (int k = 0; k < H / 4; ++k) {
                float4 w = w4[k], a = a4[k], o = o4[k];
                float ww;
                ww = w.x * w.x; d += ww * a.x * o.x; na += ww * a.x * a.x; nb += ww * o.x * o.x;
                ww = w.y * w.y; d += ww * a.y * o.y; na += ww * a.y * a.y; nb += ww * o.y * o.y;
                ww = w.z * w.z; d += ww * a.z * o.z; na += ww * a.z * a.z; nb += ww * o.z * o.z;
                ww = w.w * w.w; d += ww * a.w * o.w; na += ww * a.w * a.w; nb += ww * o.w * o.w;
            }
            const int base = (wv == 0) ? 3 : (wv == 1) ? 64 : 85;
            orow[base + ln] = d / (fmaxf(sqrtf(na), EPSF) * fmaxf(sqrtf(nb), EPSF));
        }
    } else {
        if (ln < 3) {
            const float* oth = (ln == 0) ? sl : (ln == 1) ? sam : sax;
            const float4* a4 = (const float4*)sa;
            const float4* o4 = (const float4*)oth;
            float d = 0.f, na = 0.f, nb = 0.f;
            #pragma unroll 5
            for (int k = 0; k < H / 4; ++k) {
                float4 a = a4[k], o = o4[k];
                d += a.x * o.x + a.y * o.y + a.z * o.z + a.w * o.w;
                na += a.x * a.x + a.y * a.y + a.z * a.z + a.w * a.w;
                nb += o.x * o.x + o.y * o.y + o.z * o.z + o.w * o.w;
            }
            orow[(ln == 0) ? 2 : (ln == 1) ? 63 : 84] =
                d / (fmaxf(sqrtf(na), EPSF) * fmaxf(sqrtf(nb), EPSF));
        } else if (ln == 3) {
            orow[0] = s_scal[2];
            orow[1] = s_scal[3];
        }
    }
}

// ---------------------------------------------------------------- k_pair_mfma
// One block per (b,p); 4 waves; 128x128x128(bf16) MFMA GEMM; in-register
// masked max/mean pooling over BOTH axes. w1^2 computed inline from w1.
__global__ __launch_bounds__(256) void
k_pair_mfma(const u16* __restrict__ Ab, const u16* __restrict__ Bb,
            const float* __restrict__ w1,
            const float* __restrict__ nwA, const float* __restrict__ nwB,
            const int* __restrict__ maskA, const int* __restrict__ maskB,
            float* __restrict__ outP, float* __restrict__ outH)
{
    const int p = blockIdx.x, b = blockIdx.y, t = threadIdx.x;
    __shared__ __align__(16) u16 sB[128 * 136];
    __shared__ float snwA[128], snwB[128], smA[128], smB[128];
    __shared__ float pJmax[128], pJsum[128];
    __shared__ float pImax[4][128], pIsum[4][128];
    __shared__ float sRed[4];                          // maxA,sumA,maxB,sumB

    if (t < 128) {
        snwA[t] = nwA[(b * L + t) * P + p];
        snwB[t] = nwB[(b * L + t) * P + p];
        smA[t] = (float)maskA[b * L + t];
        smB[t] = (float)maskB[b * L + t];
    }
    __syncthreads();

    if (t < 64) {
        float a0 = smB[t], a1 = smB[t + 64];
        float mx = fmaxf(a0, a1), sm = a0 + a1;
        for (int d = 1; d < 64; d <<= 1) {
            mx = fmaxf(mx, __shfl_xor(mx, d));
            sm += __shfl_xor(sm, d);
        }
        if (t == 0) { sRed[2] = mx; sRed[3] = sm; }
    } else if (t < 128) {
        const int l = t - 64;
        float a0 = smA[l], a1 = smA[l + 64];
        float mx = fmaxf(a0, a1), sm = a0 + a1;
        for (int d = 1; d < 64; d <<= 1) {
            mx = fmaxf(mx, __shfl_xor(mx, d));
            sm += __shfl_xor(sm, d);
        }
        if (l == 0) { sRed[0] = mx; sRed[1] = sm; }
    }

    {   // stage B into LDS (bf16, K already zero-padded)
        const uint4* src = (const uint4*)(Bb + (size_t)b * L * 128);
        #pragma unroll
        for (int it = 0; it < 8; ++it) {
            int idx = it * 256 + t;
            int row = idx >> 4, kc = (idx & 15) * 8;
            uint4 v = src[idx];
            *(uint4*)&sB[row * 136 + kc] = v;
        }
    }
    __syncthreads();

    const int wave = t >> 6, lane = t & 63;
    const int m = lane & 15, q = lane >> 4;

    // w1^2 for this lane's k positions, inline from w1 (zero pad k>=H)
    float swv[4][8];
    #pragma unroll
    for (int ks = 0; ks < 4; ++ks)
        #pragma unroll
        for (int e = 0; e < 8; ++e) {
            int k = ks * 32 + q * 8 + e;
            float w = (k < H) ? w1[p * H + k] : 0.f;
            swv[ks][e] = w * w;
        }

    f4 acc[2][8];
    #pragma unroll
    for (int rt = 0; rt < 2; ++rt)
        #pragma unroll
        for (int ct = 0; ct < 8; ++ct)
            acc[rt][ct] = (f4){0.f, 0.f, 0.f, 0.f};

    const uint4* gA0 = (const uint4*)(Ab + (size_t)(b * L + wave * 32 + m) * 128);
    const uint4* gA1 = (const uint4*)(Ab + (size_t)(b * L + wave * 32 + 16 + m) * 128);

    #pragma unroll
    for (int ks = 0; ks < 4; ++ks) {
        uint4 va0 = gA0[ks * 4 + q];
        uint4 va1 = gA1[ks * 4 + q];
        sh8 a0, a1;
        {
            u32 vs0[4] = {va0.x, va0.y, va0.z, va0.w};
            u32 vs1[4] = {va1.x, va1.y, va1.z, va1.w};
            u32 r0[4], r1[4];
            #pragma unroll
            for (int e = 0; e < 4; ++e) {
                float f0 = bf2f(vs0[e] & 0xffffu) * swv[ks][2 * e];
                float f1 = bf2f(vs0[e] >> 16) * swv[ks][2 * e + 1];
                r0[e] = (u32)f2bf(f0) | ((u32)f2bf(f1) << 16);
                float g0 = bf2f(vs1[e] & 0xffffu) * swv[ks][2 * e];
                float g1 = bf2f(vs1[e] >> 16) * swv[ks][2 * e + 1];
                r1[e] = (u32)f2bf(g0) | ((u32)f2bf(g1) << 16);
            }
            uint4 o0 = {r0[0], r0[1], r0[2], r0[3]};
            uint4 o1 = {r1[0], r1[1], r1[2], r1[3]};
            a0 = __builtin_bit_cast(sh8, o0);
            a1 = __builtin_bit_cast(sh8, o1);
        }
        const int ko = ks * 32 + q * 8;
        #pragma unroll
        for (int ct = 0; ct < 8; ++ct) {
            sh8 bb = *(const sh8*)&sB[(ct * 16 + m) * 136 + ko];
            acc[0][ct] = __builtin_amdgcn_mfma_f32_16x16x32_bf16(a0, bb, acc[0][ct], 0, 0, 0);
            acc[1][ct] = __builtin_amdgcn_mfma_f32_16x16x32_bf16(a1, bb, acc[1][ct], 0, 0, 0);
        }
    }

    // epilogue: mv = acc / max(nwA*nwB, eps); pool over j and i
    float nB[8], mBv[8], imax[8], isum[8];
    #pragma unroll
    for (int ct = 0; ct < 8; ++ct) {
        const int j = ct * 16 + m;
        nB[ct] = snwB[j]; mBv[ct] = smB[j];
        imax[ct] = MINV; isum[ct] = 0.f;
    }
    #pragma unroll
    for (int rt = 0; rt < 2; ++rt) {
        #pragma unroll
        for (int reg = 0; reg < 4; ++reg) {
            const int i = wave * 32 + rt * 16 + q * 4 + reg;
            const float na = snwA[i];
            const float ma = smA[i];
            float jmax = MINV, jsum = 0.f;
            #pragma unroll
            for (int ct = 0; ct < 8; ++ct) {
                float v = acc[rt][ct][reg] *
                          __builtin_amdgcn_rcpf(fmaxf(na * nB[ct], EPSF));
                jmax = fmaxf(jmax, mBv[ct] > 0.f ? v : MINV);
                jsum += mBv[ct] > 0.f ? v : 0.f;
                imax[ct] = fmaxf(imax[ct], ma > 0.f ? v : MINV);
                isum[ct] += ma > 0.f ? v : 0.f;
            }
            for (int d = 1; d < 16; d <<= 1) {
                jmax = fmaxf(jmax, __shfl_xor(jmax, d));
                jsum += __shfl_xor(jsum, d);
            }
            if (m == 0) { pJmax[i] = jmax; pJsum[i] = jsum; }
        }
    }
    #pragma unroll
    for (int ct = 0; ct < 8; ++ct) {
        float mx = imax[ct], sm = isum[ct];
        mx = fmaxf(mx, __shfl_xor(mx, 16)); sm += __shfl_xor(sm, 16);
        mx = fmaxf(mx, __shfl_xor(mx, 32)); sm += __shfl_xor(sm, 32);
        if (q == 0) { const int j = ct * 16 + m; pImax[wave][j] = mx; pIsum[wave][j] = sm; }
    }
    __syncthreads();

    if (t < 128) {
        const int i = t;
        const float ma = smA[i];
        const float mm = ma * sRed[2];
        const float cnt = ma * sRed[3];
        float* orow = outP + (b * L + i) * C;
        orow[23 + p] = pJmax[i] * mm;
        orow[43 + p] = ma * pJsum[i] / fmaxf(cnt, EPSF);

        const float mb = smB[i];
        const float hmax = fmaxf(fmaxf(pImax[0][i], pImax[1][i]),
                                 fmaxf(pImax[2][i], pImax[3][i]));
        const float hsum = pIsum[0][i] + pIsum[1][i] + pIsum[2][i] + pIsum[3][i];
        float* hrow = outH + (b * L + i) * C;
        hrow[23 + p] = hmax * mb * sRed[0];
        hrow[43 + p] = mb * hsum / fmaxf(mb * sRed[1], EPSF);
    }
}

// ---------------------------------------------------------------- launch
extern "C" void kernel_launch(void* const* d_in, const int* in_sizes, int n_in,
                              void* d_out, int out_size, void* d_ws, size_t ws_size,
                              hipStream_t stream)
{
    const float* ctx_p = (const float*)d_in[0];
    const int*   mask_p = (const int*)d_in[1];
    const float* ctx_h = (const float*)d_in[2];
    const int*   mask_h = (const int*)d_in[3];
    const float* w0 = (const float*)d_in[4];
    const float* w1 = (const float*)d_in[5];
    const float* w2 = (const float*)d_in[6];
    const float* w3 = (const float*)d_in[7];
    float* out = (float*)d_out;

    float* ws   = (float*)d_ws;
    float* cp   = ws;                       // B*L*H
    float* ch   = cp   + B * L * H;
    float* np_  = ch   + B * L * H;         // B*L
    float* nh_  = np_  + B * L;
    float* nw1p = nh_  + B * L;             // B*L*P
    float* nw1h = nw1p + B * L * P;
    u16*   cpb  = (u16*)(nw1h + B * L * P); // B*L*128 u16
    u16*   chb  = cpb + B * L * 128;

    float* out_h = out + B * L * C;

    k_prep<<<dim3(L, B, 2), dim3(128), 0, stream>>>(
        ctx_p, mask_p, ctx_h, mask_h, w1,
        cp, ch, cpb, chb, np_, nh_, nw1p, nw1h);
    k_pair_mfma<<<dim3(P, B), dim3(256), 0, stream>>>(
        cpb, chb, w1, nw1p, nw1h, mask_p, mask_h, out, out_h);
    k_side<<<dim3(L, B, 2), dim3(256), 0, stream>>>(
        cp, ch, np_, nh_, mask_p, mask_h, w0, w2, w3, out);
}

// Round 4
// 176.259 us; speedup vs baseline: 1.3278x; 1.3278x over previous
//
#include <hip/hip_runtime.h>
#include <math.h>

// MatchingLayer (BiMPM-style) — MI355X. Round 4: cos-as-MFMA (identity weight
// block in k_pair), small-LDS high-occupancy k_side. 3 dispatches.
// B=32, L=128, H=100, P=20, C=105.

namespace {
constexpr int B = 32;
constexpr int L = 128;
constexpr int H = 100;
constexpr int P = 20;
constexpr int C = 105;
constexpr float EPSF = 1e-8f;
constexpr float MINV = -1e7f;
}

typedef unsigned short u16;
typedef unsigned int u32;
typedef short sh8 __attribute__((ext_vector_type(8)));   // 8 bf16 (4 VGPRs)
typedef float f4 __attribute__((ext_vector_type(4)));

__device__ __forceinline__ u16 f2bf(float f) {           // RNE f32->bf16
    u32 u = __float_as_uint(f);
    u += 0x7FFFu + ((u >> 16) & 1u);
    return (u16)(u >> 16);
}
__device__ __forceinline__ float bf2f(u32 h) {
    return __uint_as_float(h << 16);
}

// ---------------------------------------------------------------- k_prep
// grid (L,B,2), block 128. Masked vector (fp32 + bf16 K=128 padded copy),
// plain norm, P w1-weighted norms.
__global__ void k_prep(const float* __restrict__ ctx_p, const int* __restrict__ mask_p,
                       const float* __restrict__ ctx_h, const int* __restrict__ mask_h,
                       const float* __restrict__ w1,
                       float* __restrict__ cp, float* __restrict__ ch,
                       u16* __restrict__ cpb, u16* __restrict__ chb,
                       float* __restrict__ np_, float* __restrict__ nh_,
                       float* __restrict__ nwp, float* __restrict__ nwh)
{
    const int b = blockIdx.y, i = blockIdx.x, side = blockIdx.z, t = threadIdx.x;
    const float* ctx = side ? ctx_h : ctx_p;
    const int*  mask = side ? mask_h : mask_p;
    float* dst  = side ? ch  : cp;
    u16*   dstb = side ? chb : cpb;
    float* nrm  = side ? nh_ : np_;
    float* nw   = side ? nwh : nwp;

    const int row = b * L + i;
    __shared__ __align__(16) float sv2[H];
    const float m = (float)mask[row];
    float v = 0.f;
    if (t < H) {
        v = ctx[row * H + t] * m;
        dst[row * H + t] = v;
        sv2[t] = v * v;
    }
    dstb[row * 128 + t] = f2bf(v);   // zero pad for t>=H
    __syncthreads();
    if (t < P) {
        const float4* w4 = (const float4*)(w1 + t * H);
        const float4* v4 = (const float4*)sv2;
        float acc = 0.f;
        #pragma unroll
        for (int k = 0; k < H / 4; ++k) {
            float4 w = w4[k], s = v4[k];
            acc += w.x * w.x * s.x + w.y * w.y * s.y + w.z * w.z * s.z + w.w * w.w * s.w;
        }
        nw[row * P + t] = sqrtf(acc);
    } else if (t == P) {
        const float4* v4 = (const float4*)sv2;
        float acc = 0.f;
        #pragma unroll
        for (int k = 0; k < H / 4; ++k) {
            float4 s = v4[k];
            acc += s.x + s.y + s.z + s.w;
        }
        nrm[row] = sqrtf(acc);
    }
}

// ---------------------------------------------------------------- k_pair_mfma
// grid (P+1, B), 256 thr. p<20: w1^2-weighted 128x128x128 bf16 GEMM + masked
// max/mean pooling over both axes. p==20: identity weights -> cosine matrix,
// writes cosM (p-side rows) and cosT (h-side rows).
__global__ __launch_bounds__(256) void
k_pair_mfma(const u16* __restrict__ Ab, const u16* __restrict__ Bb,
            const float* __restrict__ w1,
            const float* __restrict__ nwA, const float* __restrict__ nwB,
            const float* __restrict__ np_, const float* __restrict__ nh_,
            const int* __restrict__ maskA, const int* __restrict__ maskB,
            float* __restrict__ outP, float* __restrict__ outH,
            float* __restrict__ cosM, float* __restrict__ cosT)
{
    const int p = blockIdx.x, b = blockIdx.y, t = threadIdx.x;
    const bool is_cos = (p == P);
    __shared__ __align__(16) u16 sB[128 * 136];
    __shared__ float snwA[128], snwB[128], smA[128], smB[128];
    __shared__ float pJmax[128], pJsum[128];
    __shared__ float pImax[4][128], pIsum[4][128];
    __shared__ float sRed[4];                          // maxA,sumA,maxB,sumB

    if (t < 128) {
        snwA[t] = is_cos ? np_[b * L + t] : nwA[(b * L + t) * P + p];
        snwB[t] = is_cos ? nh_[b * L + t] : nwB[(b * L + t) * P + p];
        smA[t] = (float)maskA[b * L + t];
        smB[t] = (float)maskB[b * L + t];
    }
    __syncthreads();

    if (!is_cos) {
        if (t < 64) {
            float a0 = smB[t], a1 = smB[t + 64];
            float mx = fmaxf(a0, a1), sm = a0 + a1;
            for (int d = 1; d < 64; d <<= 1) {
                mx = fmaxf(mx, __shfl_xor(mx, d));
                sm += __shfl_xor(sm, d);
            }
            if (t == 0) { sRed[2] = mx; sRed[3] = sm; }
        } else if (t < 128) {
            const int l = t - 64;
            float a0 = smA[l], a1 = smA[l + 64];
            float mx = fmaxf(a0, a1), sm = a0 + a1;
            for (int d = 1; d < 64; d <<= 1) {
                mx = fmaxf(mx, __shfl_xor(mx, d));
                sm += __shfl_xor(sm, d);
            }
            if (l == 0) { sRed[0] = mx; sRed[1] = sm; }
        }
    }

    {   // stage B into LDS (bf16, K already zero-padded)
        const uint4* src = (const uint4*)(Bb + (size_t)b * L * 128);
        #pragma unroll
        for (int it = 0; it < 8; ++it) {
            int idx = it * 256 + t;
            int row = idx >> 4, kc = (idx & 15) * 8;
            uint4 v = src[idx];
            *(uint4*)&sB[row * 136 + kc] = v;
        }
    }
    __syncthreads();

    const int wave = t >> 6, lane = t & 63;
    const int m = lane & 15, q = lane >> 4;

    // weights^2 for this lane's k positions (identity for the cos block)
    float swv[4][8];
    #pragma unroll
    for (int ks = 0; ks < 4; ++ks)
        #pragma unroll
        for (int e = 0; e < 8; ++e) {
            int k = ks * 32 + q * 8 + e;
            if (is_cos) swv[ks][e] = (k < H) ? 1.f : 0.f;
            else {
                float w = (k < H) ? w1[p * H + k] : 0.f;
                swv[ks][e] = w * w;
            }
        }

    f4 acc[2][8];
    #pragma unroll
    for (int rt = 0; rt < 2; ++rt)
        #pragma unroll
        for (int ct = 0; ct < 8; ++ct)
            acc[rt][ct] = (f4){0.f, 0.f, 0.f, 0.f};

    const uint4* gA0 = (const uint4*)(Ab + (size_t)(b * L + wave * 32 + m) * 128);
    const uint4* gA1 = (const uint4*)(Ab + (size_t)(b * L + wave * 32 + 16 + m) * 128);

    #pragma unroll
    for (int ks = 0; ks < 4; ++ks) {
        uint4 va0 = gA0[ks * 4 + q];
        uint4 va1 = gA1[ks * 4 + q];
        sh8 a0, a1;
        {
            u32 vs0[4] = {va0.x, va0.y, va0.z, va0.w};
            u32 vs1[4] = {va1.x, va1.y, va1.z, va1.w};
            u32 r0[4], r1[4];
            #pragma unroll
            for (int e = 0; e < 4; ++e) {
                float f0 = bf2f(vs0[e] & 0xffffu) * swv[ks][2 * e];
                float f1 = bf2f(vs0[e] >> 16) * swv[ks][2 * e + 1];
                r0[e] = (u32)f2bf(f0) | ((u32)f2bf(f1) << 16);
                float g0 = bf2f(vs1[e] & 0xffffu) * swv[ks][2 * e];
                float g1 = bf2f(vs1[e] >> 16) * swv[ks][2 * e + 1];
                r1[e] = (u32)f2bf(g0) | ((u32)f2bf(g1) << 16);
            }
            uint4 o0 = {r0[0], r0[1], r0[2], r0[3]};
            uint4 o1 = {r1[0], r1[1], r1[2], r1[3]};
            a0 = __builtin_bit_cast(sh8, o0);
            a1 = __builtin_bit_cast(sh8, o1);
        }
        const int ko = ks * 32 + q * 8;
        #pragma unroll
        for (int ct = 0; ct < 8; ++ct) {
            sh8 bb = *(const sh8*)&sB[(ct * 16 + m) * 136 + ko];
            acc[0][ct] = __builtin_amdgcn_mfma_f32_16x16x32_bf16(a0, bb, acc[0][ct], 0, 0, 0);
            acc[1][ct] = __builtin_amdgcn_mfma_f32_16x16x32_bf16(a1, bb, acc[1][ct], 0, 0, 0);
        }
    }

    if (is_cos) {
        // cos[i][j] = acc / max(np[i]*nh[j], eps) -> cosM rows (p) + cosT rows (h)
        float nB[8];
        #pragma unroll
        for (int ct = 0; ct < 8; ++ct) nB[ct] = snwB[ct * 16 + m];
        #pragma unroll
        for (int rt = 0; rt < 2; ++rt) {
            #pragma unroll
            for (int reg = 0; reg < 4; ++reg) {
                const int i = wave * 32 + rt * 16 + q * 4 + reg;
                const float na = snwA[i];
                #pragma unroll
                for (int ct = 0; ct < 8; ++ct) {
                    const int j = ct * 16 + m;
                    float v = acc[rt][ct][reg] *
                              __builtin_amdgcn_rcpf(fmaxf(na * nB[ct], EPSF));
                    cosM[((size_t)b * L + i) * L + j] = v;
                    cosT[((size_t)b * L + j) * L + i] = v;
                }
            }
        }
        return;
    }

    // epilogue: mv = acc / max(nwA*nwB, eps); pool over j and i
    float nB[8], mBv[8], imax[8], isum[8];
    #pragma unroll
    for (int ct = 0; ct < 8; ++ct) {
        const int j = ct * 16 + m;
        nB[ct] = snwB[j]; mBv[ct] = smB[j];
        imax[ct] = MINV; isum[ct] = 0.f;
    }
    #pragma unroll
    for (int rt = 0; rt < 2; ++rt) {
        #pragma unroll
        for (int reg = 0; reg < 4; ++reg) {
            const int i = wave * 32 + rt * 16 + q * 4 + reg;
            const float na = snwA[i];
            const float ma = smA[i];
            float jmax = MINV, jsum = 0.f;
            #pragma unroll
            for (int ct = 0; ct < 8; ++ct) {
                float v = acc[rt][ct][reg] *
                          __builtin_amdgcn_rcpf(fmaxf(na * nB[ct], EPSF));
                jmax = fmaxf(jmax, mBv[ct] > 0.f ? v : MINV);
                jsum += mBv[ct] > 0.f ? v : 0.f;
                imax[ct] = fmaxf(imax[ct], ma > 0.f ? v : MINV);
                isum[ct] += ma > 0.f ? v : 0.f;
            }
            for (int d = 1; d < 16; d <<= 1) {
                jmax = fmaxf(jmax, __shfl_xor(jmax, d));
                jsum += __shfl_xor(jsum, d);
            }
            if (m == 0) { pJmax[i] = jmax; pJsum[i] = jsum; }
        }
    }
    #pragma unroll
    for (int ct = 0; ct < 8; ++ct) {
        float mx = imax[ct], sm = isum[ct];
        mx = fmaxf(mx, __shfl_xor(mx, 16)); sm += __shfl_xor(sm, 16);
        mx = fmaxf(mx, __shfl_xor(mx, 32)); sm += __shfl_xor(sm, 32);
        if (q == 0) { const int j = ct * 16 + m; pImax[wave][j] = mx; pIsum[wave][j] = sm; }
    }
    __syncthreads();

    if (t < 128) {
        const int i = t;
        const float ma = smA[i];
        const float mm = ma * sRed[2];
        const float cnt = ma * sRed[3];
        float* orow = outP + ((size_t)b * L + i) * C;
        orow[23 + p] = pJmax[i] * mm;
        orow[43 + p] = ma * pJsum[i] / fmaxf(cnt, EPSF);

        const float mb = smB[i];
        const float hmax = fmaxf(fmaxf(pImax[0][i], pImax[1][i]),
                                 fmaxf(pImax[2][i], pImax[3][i]));
        const float hsum = pIsum[0][i] + pIsum[1][i] + pIsum[2][i] + pIsum[3][i];
        float* hrow = outH + ((size_t)b * L + i) * C;
        hrow[23 + p] = hmax * mb * sRed[0];
        hrow[43 + p] = mb * hsum / fmaxf(mb * sRed[1], EPSF);
    }
}

// ---------------------------------------------------------------- k_side
// grid (L,B,2), block 256, ~8 KB LDS (high occupancy). Reads precomputed cos
// row coalesced; attentive j-loop split over 4 waves (j-quarters); weighted
// epilogue dots 3-way K-split over 60 lanes/wave.
__global__ __launch_bounds__(256) void
k_side(const float* __restrict__ cp, const float* __restrict__ ch,
       const float* __restrict__ cosM, const float* __restrict__ cosT,
       const int* __restrict__ mask_p, const int* __restrict__ mask_h,
       const float* __restrict__ w0, const float* __restrict__ w2,
       const float* __restrict__ w3, float* __restrict__ out)
{
    const int b = blockIdx.y, i = blockIdx.x, side = blockIdx.z, t = threadIdx.x;
    const float* A   = side ? ch : cp;
    const float* Bv  = side ? cp : ch;
    const int* maskA = side ? mask_h : mask_p;
    const int* maskB = side ? mask_p : mask_h;
    const float* cosRow = (side ? cosT : cosM) + ((size_t)b * L + i) * L;
    float* orow = out + ((size_t)side * B * L + (size_t)b * L + i) * C;

    __shared__ __align__(16) float sa[H], sl[H], sam[H], sax[H];
    __shared__ float scos[L], smb[L];
    __shared__ float pam[4][112], pax[4][112];
    __shared__ float s_scal[4];   // sumcos, mmax, cosmax, cosmean

    const float mA = (float)maskA[b * L + i];
    if (t < 128) {
        if (t < H) sa[t] = A[((size_t)b * L + i) * H + t];
        scos[t] = cosRow[t];
        smb[t] = mA * (float)maskB[b * L + t];
    } else {
        // waves 2-3: last-index of B side + load last vector
        const int tt = t - 128;
        const int l = tt & 63;
        float s0 = (float)maskB[b * L + l] + (float)maskB[b * L + l + 64];
        for (int d = 1; d < 64; d <<= 1) s0 += __shfl_xor(s0, d);
        int idx = (int)s0 - 1; if (idx < 0) idx = 0;
        if (tt < H) sl[tt] = Bv[((size_t)b * L + idx) * H + tt];
    }
    __syncthreads();

    const int wv = t >> 6, ln = t & 63;

    if (wv == 0) {  // block-wide scalars
        float c0 = scos[ln], c1 = scos[ln + 64];
        float b0 = smb[ln], b1 = smb[ln + 64];
        float sc = c0 + c1;
        float sm = c0 * b0 + c1 * b1;
        float cn = b0 + b1;
        float mm = fmaxf(b0, b1);
        float vm = fmaxf(b0 > 0.f ? c0 : MINV, b1 > 0.f ? c1 : MINV);
        for (int d = 1; d < 64; d <<= 1) {
            sc += __shfl_xor(sc, d);
            sm += __shfl_xor(sm, d);
            cn += __shfl_xor(cn, d);
            mm = fmaxf(mm, __shfl_xor(mm, d));
            vm = fmaxf(vm, __shfl_xor(vm, d));
        }
        if (ln == 0) {
            s_scal[0] = sc; s_scal[1] = mm;
            s_scal[2] = vm * mm;
            s_scal[3] = sm / fmaxf(cn, EPSF);
        }
    }
    {   // attentive partials: wave wv covers j in [wv*32, wv*32+32)
        const int j0 = wv * 32;
        const int tt2 = ln + 64;
        float am0 = 0.f, ax0 = MINV, am1 = 0.f, ax1 = MINV;
        for (int j = j0; j < j0 + 32; ++j) {
            const float* bp = Bv + ((size_t)b * L + j) * H;
            float cj = scos[j];
            bool mj = smb[j] > 0.f;
            float v0 = cj * bp[ln];
            am0 += v0;
            ax0 = fmaxf(ax0, mj ? v0 : MINV);
            if (tt2 < H) {
                float v1 = cj * bp[tt2];
                am1 += v1;
                ax1 = fmaxf(ax1, mj ? v1 : MINV);
            }
        }
        pam[wv][ln] = am0; pax[wv][ln] = ax0;
        if (tt2 < H) { pam[wv][tt2] = am1; pax[wv][tt2] = ax1; }
    }
    __syncthreads();
    if (t < H) {
        sam[t] = (pam[0][t] + pam[1][t] + pam[2][t] + pam[3][t]) / fmaxf(s_scal[0], EPSF);
        sax[t] = fmaxf(fmaxf(pax[0][t], pax[1][t]), fmaxf(pax[2][t], pax[3][t])) * s_scal[1];
    }
    __syncthreads();

    if (wv == 0) {
        if (ln < 3) {   // unweighted sims vs sl / sam / sax
            const float* oth = (ln == 0) ? sl : (ln == 1) ? sam : sax;
            const float4* a4 = (const float4*)sa;
            const float4* o4 = (const float4*)oth;
            float d = 0.f, na = 0.f, nb = 0.f;
            #pragma unroll 5
            for (int k = 0; k < H / 4; ++k) {
                float4 a = a4[k], o = o4[k];
                d += a.x * o.x + a.y * o.y + a.z * o.z + a.w * o.w;
                na += a.x * a.x + a.y * a.y + a.z * a.z + a.w * a.w;
                nb += o.x * o.x + o.y * o.y + o.z * o.z + o.w * o.w;
            }
            orow[(ln == 0) ? 2 : (ln == 1) ? 63 : 84] =
                d / (fmaxf(sqrtf(na), EPSF) * fmaxf(sqrtf(nb), EPSF));
        } else if (ln == 3) {
            orow[0] = s_scal[2];
            orow[1] = s_scal[3];
        }
    } else if (ln < 60) {
        // waves 1..3 -> (w0,sl), (w2,sam), (w3,sax); 3-way K split per channel
        const float* wmat = (wv == 1) ? w0 : (wv == 2) ? w2 : w3;
        const float* oth  = (wv == 1) ? sl : (wv == 2) ? sam : sax;
        const int c = ln / 3, seg = ln - 3 * c;
        const int k0 = (seg == 0) ? 0 : (seg == 1) ? 9 : 17;
        const int k1 = (seg == 0) ? 9 : (seg == 1) ? 17 : 25;
        const float4* w4 = (const float4*)(wmat + c * H);
        const float4* a4 = (const float4*)sa;
        const float4* o4 = (const float4*)oth;
        float d = 0.f, na = 0.f, nb = 0.f;
        for (int k = k0; k < k1; ++k) {
            float4 w = w4[k], a = a4[k], o = o4[k];
            float ww;
            ww = w.x * w.x; d += ww * a.x * o.x; na += ww * a.x * a.x; nb += ww * o.x * o.x;
            ww = w.y * w.y; d += ww * a.y * o.y; na += ww * a.y * a.y; nb += ww * o.y * o.y;
            ww = w.z * w.z; d += ww * a.z * o.z; na += ww * a.z * a.z; nb += ww * o.z * o.z;
            ww = w.w * w.w; d += ww * a.w * o.w; na += ww * a.w * a.w; nb += ww * o.w * o.w;
        }
        d  += __shfl(d, ln + 1)  + __shfl(d, ln + 2);
        na += __shfl(na, ln + 1) + __shfl(na, ln + 2);
        nb += __shfl(nb, ln + 1) + __shfl(nb, ln + 2);
        if (seg == 0) {
            const int base = (wv == 1) ? 3 : (wv == 2) ? 64 : 85;
            orow[base + c] = d / (fmaxf(sqrtf(na), EPSF) * fmaxf(sqrtf(nb), EPSF));
        }
    }
}

// ---------------------------------------------------------------- launch
extern "C" void kernel_launch(void* const* d_in, const int* in_sizes, int n_in,
                              void* d_out, int out_size, void* d_ws, size_t ws_size,
                              hipStream_t stream)
{
    const float* ctx_p = (const float*)d_in[0];
    const int*   mask_p = (const int*)d_in[1];
    const float* ctx_h = (const float*)d_in[2];
    const int*   mask_h = (const int*)d_in[3];
    const float* w0 = (const float*)d_in[4];
    const float* w1 = (const float*)d_in[5];
    const float* w2 = (const float*)d_in[6];
    const float* w3 = (const float*)d_in[7];
    float* out = (float*)d_out;

    float* ws   = (float*)d_ws;
    float* cp   = ws;                       // B*L*H
    float* ch   = cp   + B * L * H;
    float* np_  = ch   + B * L * H;         // B*L
    float* nh_  = np_  + B * L;
    float* nw1p = nh_  + B * L;             // B*L*P
    float* nw1h = nw1p + B * L * P;
    float* cosM = nw1h + B * L * P;         // B*L*L
    float* cosT = cosM + B * L * L;         // B*L*L
    u16*   cpb  = (u16*)(cosT + B * L * L); // B*L*128 u16
    u16*   chb  = cpb + B * L * 128;

    float* out_h = out + B * L * C;

    k_prep<<<dim3(L, B, 2), dim3(128), 0, stream>>>(
        ctx_p, mask_p, ctx_h, mask_h, w1,
        cp, ch, cpb, chb, np_, nh_, nw1p, nw1h);
    k_pair_mfma<<<dim3(P + 1, B), dim3(256), 0, stream>>>(
        cpb, chb, w1, nw1p, nw1h, np_, nh_, mask_p, mask_h,
        out, out_h, cosM, cosT);
    k_side<<<dim3(L, B, 2), dim3(256), 0, stream>>>(
        cp, ch, cosM, cosT, mask_p, mask_h, w0, w2, w3, out);
}

// Round 5
// 149.001 us; speedup vs baseline: 1.5708x; 1.1829x over previous
//
#include <hip/hip_runtime.h>
#include <math.h>

// MatchingLayer (BiMPM-style) — MI355X. Round 5: i-tiled k_side (8 rows/block,
// Bv staged once as bf16 in LDS, fused attentive mean/max from LDS).
// B=32, L=128, H=100, P=20, C=105.

namespace {
constexpr int B = 32;
constexpr int L = 128;
constexpr int H = 100;
constexpr int P = 20;
constexpr int C = 105;
constexpr int TI = 8;          // i-rows per k_side block
constexpr float EPSF = 1e-8f;
constexpr float MINV = -1e7f;
}

typedef unsigned short u16;
typedef unsigned int u32;
typedef short sh8 __attribute__((ext_vector_type(8)));   // 8 bf16 (4 VGPRs)
typedef float f4 __attribute__((ext_vector_type(4)));

__device__ __forceinline__ u16 f2bf(float f) {           // RNE f32->bf16
    u32 u = __float_as_uint(f);
    u += 0x7FFFu + ((u >> 16) & 1u);
    return (u16)(u >> 16);
}
__device__ __forceinline__ float bf2f(u32 h) {
    return __uint_as_float(h << 16);
}

// ---------------------------------------------------------------- k_prep
// grid (L,B,2), block 128. Masked vector (fp32 + bf16 K=128 padded copy),
// plain norm, P w1-weighted norms.
__global__ void k_prep(const float* __restrict__ ctx_p, const int* __restrict__ mask_p,
                       const float* __restrict__ ctx_h, const int* __restrict__ mask_h,
                       const float* __restrict__ w1,
                       float* __restrict__ cp, float* __restrict__ ch,
                       u16* __restrict__ cpb, u16* __restrict__ chb,
                       float* __restrict__ np_, float* __restrict__ nh_,
                       float* __restrict__ nwp, float* __restrict__ nwh)
{
    const int b = blockIdx.y, i = blockIdx.x, side = blockIdx.z, t = threadIdx.x;
    const float* ctx = side ? ctx_h : ctx_p;
    const int*  mask = side ? mask_h : mask_p;
    float* dst  = side ? ch  : cp;
    u16*   dstb = side ? chb : cpb;
    float* nrm  = side ? nh_ : np_;
    float* nw   = side ? nwh : nwp;

    const int row = b * L + i;
    __shared__ __align__(16) float sv2[H];
    const float m = (float)mask[row];
    float v = 0.f;
    if (t < H) {
        v = ctx[row * H + t] * m;
        dst[row * H + t] = v;
        sv2[t] = v * v;
    }
    dstb[row * 128 + t] = f2bf(v);   // zero pad for t>=H
    __syncthreads();
    if (t < P) {
        const float4* w4 = (const float4*)(w1 + t * H);
        const float4* v4 = (const float4*)sv2;
        float acc = 0.f;
        #pragma unroll
        for (int k = 0; k < H / 4; ++k) {
            float4 w = w4[k], s = v4[k];
            acc += w.x * w.x * s.x + w.y * w.y * s.y + w.z * w.z * s.z + w.w * w.w * s.w;
        }
        nw[row * P + t] = sqrtf(acc);
    } else if (t == P) {
        const float4* v4 = (const float4*)sv2;
        float acc = 0.f;
        #pragma unroll
        for (int k = 0; k < H / 4; ++k) {
            float4 s = v4[k];
            acc += s.x + s.y + s.z + s.w;
        }
        nrm[row] = sqrtf(acc);
    }
}

// ---------------------------------------------------------------- k_pair_mfma
// grid (P+1, B), 256 thr. p<20: w1^2-weighted 128x128x128 bf16 GEMM + masked
// max/mean pooling over both axes. p==20: identity weights -> cosine matrix,
// writes cosM (p-side rows) and cosT (h-side rows).
__global__ __launch_bounds__(256) void
k_pair_mfma(const u16* __restrict__ Ab, const u16* __restrict__ Bb,
            const float* __restrict__ w1,
            const float* __restrict__ nwA, const float* __restrict__ nwB,
            const float* __restrict__ np_, const float* __restrict__ nh_,
            const int* __restrict__ maskA, const int* __restrict__ maskB,
            float* __restrict__ outP, float* __restrict__ outH,
            float* __restrict__ cosM, float* __restrict__ cosT)
{
    const int p = blockIdx.x, b = blockIdx.y, t = threadIdx.x;
    const bool is_cos = (p == P);
    __shared__ __align__(16) u16 sB[128 * 136];
    __shared__ float snwA[128], snwB[128], smA[128], smB[128];
    __shared__ float pJmax[128], pJsum[128];
    __shared__ float pImax[4][128], pIsum[4][128];
    __shared__ float sRed[4];                          // maxA,sumA,maxB,sumB

    if (t < 128) {
        snwA[t] = is_cos ? np_[b * L + t] : nwA[(b * L + t) * P + p];
        snwB[t] = is_cos ? nh_[b * L + t] : nwB[(b * L + t) * P + p];
        smA[t] = (float)maskA[b * L + t];
        smB[t] = (float)maskB[b * L + t];
    }
    __syncthreads();

    if (!is_cos) {
        if (t < 64) {
            float a0 = smB[t], a1 = smB[t + 64];
            float mx = fmaxf(a0, a1), sm = a0 + a1;
            for (int d = 1; d < 64; d <<= 1) {
                mx = fmaxf(mx, __shfl_xor(mx, d));
                sm += __shfl_xor(sm, d);
            }
            if (t == 0) { sRed[2] = mx; sRed[3] = sm; }
        } else if (t < 128) {
            const int l = t - 64;
            float a0 = smA[l], a1 = smA[l + 64];
            float mx = fmaxf(a0, a1), sm = a0 + a1;
            for (int d = 1; d < 64; d <<= 1) {
                mx = fmaxf(mx, __shfl_xor(mx, d));
                sm += __shfl_xor(sm, d);
            }
            if (l == 0) { sRed[0] = mx; sRed[1] = sm; }
        }
    }

    {   // stage B into LDS (bf16, K already zero-padded)
        const uint4* src = (const uint4*)(Bb + (size_t)b * L * 128);
        #pragma unroll
        for (int it = 0; it < 8; ++it) {
            int idx = it * 256 + t;
            int row = idx >> 4, kc = (idx & 15) * 8;
            uint4 v = src[idx];
            *(uint4*)&sB[row * 136 + kc] = v;
        }
    }
    __syncthreads();

    const int wave = t >> 6, lane = t & 63;
    const int m = lane & 15, q = lane >> 4;

    // weights^2 for this lane's k positions (identity for the cos block)
    float swv[4][8];
    #pragma unroll
    for (int ks = 0; ks < 4; ++ks)
        #pragma unroll
        for (int e = 0; e < 8; ++e) {
            int k = ks * 32 + q * 8 + e;
            if (is_cos) swv[ks][e] = (k < H) ? 1.f : 0.f;
            else {
                float w = (k < H) ? w1[p * H + k] : 0.f;
                swv[ks][e] = w * w;
            }
        }

    f4 acc[2][8];
    #pragma unroll
    for (int rt = 0; rt < 2; ++rt)
        #pragma unroll
        for (int ct = 0; ct < 8; ++ct)
            acc[rt][ct] = (f4){0.f, 0.f, 0.f, 0.f};

    const uint4* gA0 = (const uint4*)(Ab + (size_t)(b * L + wave * 32 + m) * 128);
    const uint4* gA1 = (const uint4*)(Ab + (size_t)(b * L + wave * 32 + 16 + m) * 128);

    #pragma unroll
    for (int ks = 0; ks < 4; ++ks) {
        uint4 va0 = gA0[ks * 4 + q];
        uint4 va1 = gA1[ks * 4 + q];
        sh8 a0, a1;
        {
            u32 vs0[4] = {va0.x, va0.y, va0.z, va0.w};
            u32 vs1[4] = {va1.x, va1.y, va1.z, va1.w};
            u32 r0[4], r1[4];
            #pragma unroll
            for (int e = 0; e < 4; ++e) {
                float f0 = bf2f(vs0[e] & 0xffffu) * swv[ks][2 * e];
                float f1 = bf2f(vs0[e] >> 16) * swv[ks][2 * e + 1];
                r0[e] = (u32)f2bf(f0) | ((u32)f2bf(f1) << 16);
                float g0 = bf2f(vs1[e] & 0xffffu) * swv[ks][2 * e];
                float g1 = bf2f(vs1[e] >> 16) * swv[ks][2 * e + 1];
                r1[e] = (u32)f2bf(g0) | ((u32)f2bf(g1) << 16);
            }
            uint4 o0 = {r0[0], r0[1], r0[2], r0[3]};
            uint4 o1 = {r1[0], r1[1], r1[2], r1[3]};
            a0 = __builtin_bit_cast(sh8, o0);
            a1 = __builtin_bit_cast(sh8, o1);
        }
        const int ko = ks * 32 + q * 8;
        #pragma unroll
        for (int ct = 0; ct < 8; ++ct) {
            sh8 bb = *(const sh8*)&sB[(ct * 16 + m) * 136 + ko];
            acc[0][ct] = __builtin_amdgcn_mfma_f32_16x16x32_bf16(a0, bb, acc[0][ct], 0, 0, 0);
            acc[1][ct] = __builtin_amdgcn_mfma_f32_16x16x32_bf16(a1, bb, acc[1][ct], 0, 0, 0);
        }
    }

    if (is_cos) {
        float nB[8];
        #pragma unroll
        for (int ct = 0; ct < 8; ++ct) nB[ct] = snwB[ct * 16 + m];
        #pragma unroll
        for (int rt = 0; rt < 2; ++rt) {
            #pragma unroll
            for (int reg = 0; reg < 4; ++reg) {
                const int i = wave * 32 + rt * 16 + q * 4 + reg;
                const float na = snwA[i];
                #pragma unroll
                for (int ct = 0; ct < 8; ++ct) {
                    const int j = ct * 16 + m;
                    float v = acc[rt][ct][reg] *
                              __builtin_amdgcn_rcpf(fmaxf(na * nB[ct], EPSF));
                    cosM[((size_t)b * L + i) * L + j] = v;
                    cosT[((size_t)b * L + j) * L + i] = v;
                }
            }
        }
        return;
    }

    // epilogue: mv = acc / max(nwA*nwB, eps); pool over j and i
    float nB[8], mBv[8], imax[8], isum[8];
    #pragma unroll
    for (int ct = 0; ct < 8; ++ct) {
        const int j = ct * 16 + m;
        nB[ct] = snwB[j]; mBv[ct] = smB[j];
        imax[ct] = MINV; isum[ct] = 0.f;
    }
    #pragma unroll
    for (int rt = 0; rt < 2; ++rt) {
        #pragma unroll
        for (int reg = 0; reg < 4; ++reg) {
            const int i = wave * 32 + rt * 16 + q * 4 + reg;
            const float na = snwA[i];
            const float ma = smA[i];
            float jmax = MINV, jsum = 0.f;
            #pragma unroll
            for (int ct = 0; ct < 8; ++ct) {
                float v = acc[rt][ct][reg] *
                          __builtin_amdgcn_rcpf(fmaxf(na * nB[ct], EPSF));
                jmax = fmaxf(jmax, mBv[ct] > 0.f ? v : MINV);
                jsum += mBv[ct] > 0.f ? v : 0.f;
                imax[ct] = fmaxf(imax[ct], ma > 0.f ? v : MINV);
                isum[ct] += ma > 0.f ? v : 0.f;
            }
            for (int d = 1; d < 16; d <<= 1) {
                jmax = fmaxf(jmax, __shfl_xor(jmax, d));
                jsum += __shfl_xor(jsum, d);
            }
            if (m == 0) { pJmax[i] = jmax; pJsum[i] = jsum; }
        }
    }
    #pragma unroll
    for (int ct = 0; ct < 8; ++ct) {
        float mx = imax[ct], sm = isum[ct];
        mx = fmaxf(mx, __shfl_xor(mx, 16)); sm += __shfl_xor(sm, 16);
        mx = fmaxf(mx, __shfl_xor(mx, 32)); sm += __shfl_xor(sm, 32);
        if (q == 0) { const int j = ct * 16 + m; pImax[wave][j] = mx; pIsum[wave][j] = sm; }
    }
    __syncthreads();

    if (t < 128) {
        const int i = t;
        const float ma = smA[i];
        const float mm = ma * sRed[2];
        const float cnt = ma * sRed[3];
        float* orow = outP + ((size_t)b * L + i) * C;
        orow[23 + p] = pJmax[i] * mm;
        orow[43 + p] = ma * pJsum[i] / fmaxf(cnt, EPSF);

        const float mb = smB[i];
        const float hmax = fmaxf(fmaxf(pImax[0][i], pImax[1][i]),
                                 fmaxf(pImax[2][i], pImax[3][i]));
        const float hsum = pIsum[0][i] + pIsum[1][i] + pIsum[2][i] + pIsum[3][i];
        float* hrow = outH + ((size_t)b * L + i) * C;
        hrow[23 + p] = hmax * mb * sRed[0];
        hrow[43 + p] = mb * hsum / fmaxf(mb * sRed[1], EPSF);
    }
}

// ---------------------------------------------------------------- k_side_t
// grid (L/TI, B, 2), block 256, ~47 KB LDS (3 blocks/CU). One block = TI=8
// rows: stage Bv slice (bf16) + cos tile + A rows once, then everything from
// LDS. Wave wv handles rows {wv, wv+4}: per-row scalars (ch 0,1) + fused
// attentive mean/max loop. Phase 3: 504 channel-dot tasks over all threads.
__global__ __launch_bounds__(256, 3) void
k_side_t(const float* __restrict__ cp, const float* __restrict__ ch,
         const u16* __restrict__ cpb, const u16* __restrict__ chb,
         const float* __restrict__ cosM, const float* __restrict__ cosT,
         const int* __restrict__ mask_p, const int* __restrict__ mask_h,
         const float* __restrict__ w0, const float* __restrict__ w2,
         const float* __restrict__ w3, float* __restrict__ out)
{
    const int tile = blockIdx.x, b = blockIdx.y, side = blockIdx.z, t = threadIdx.x;
    const int i0 = tile * TI;
    const float* A   = side ? ch : cp;
    const float* Bv  = side ? cp : ch;
    const u16*  Bvb  = side ? cpb : chb;
    const int* maskA = side ? mask_h : mask_p;
    const int* maskB = side ? mask_p : mask_h;
    const float* cosSrc = side ? cosT : cosM;
    float* outBase = out + ((size_t)side * B * L + (size_t)b * L) * C;

    __shared__ __align__(16) u16  sBv[L * 128];          // 32 KB bf16 rows
    __shared__ float scos[TI][L];                        // 4 KB
    __shared__ __align__(16) float sa[TI][H];            // 3.2 KB
    __shared__ __align__(16) float sam[TI][H];           // 3.2 KB
    __shared__ __align__(16) float sax[TI][H];           // 3.2 KB
    __shared__ __align__(16) float sl[H];                // 0.4 KB
    __shared__ float smB[L];                             // 0.5 KB

    // ---- phase 1: staging
    {   // Bv slice: 128 rows x 256 B = 2048 uint4
        const uint4* src = (const uint4*)(Bvb + (size_t)b * L * 128);
        uint4* dst = (uint4*)sBv;
        #pragma unroll
        for (int r = 0; r < 8; ++r) dst[r * 256 + t] = src[r * 256 + t];
    }
    #pragma unroll
    for (int r = 0; r < TI * L / 256; ++r) {             // cos tile: 1024 floats
        int idx = r * 256 + t;
        int il = idx >> 7, j = idx & 127;
        scos[il][j] = cosSrc[((size_t)b * L + i0 + il) * L + j];
    }
    for (int idx = t; idx < TI * H; idx += 256) {        // A rows: 800 floats
        int il = idx / H, k = idx - il * H;
        sa[il][k] = A[((size_t)b * L + i0 + il) * H + k];
    }
    if (t < L) smB[t] = (float)maskB[b * L + t];
    __syncthreads();

    const int wv = t >> 6, ln = t & 63;

    if (wv == 0) {   // wave 0 extra: last-B row -> sl
        float s0 = smB[ln] + smB[ln + 64];
        for (int d = 1; d < 64; d <<= 1) s0 += __shfl_xor(s0, d);
        int idx = (int)s0 - 1; if (idx < 0) idx = 0;
        const float* lr = Bv + ((size_t)b * L + idx) * H;
        sl[ln] = lr[ln];
        if (ln + 64 < H) sl[ln + 64] = lr[ln + 64];
    }

    // ---- phase 2: wave wv owns rows wv and wv+4
    #pragma unroll
    for (int pass = 0; pass < 2; ++pass) {
        const int il = wv + pass * 4;
        const int gi = i0 + il;
        const float mA = (float)maskA[b * L + gi];
        // per-row scalars (2 j per lane, butterfly reduce)
        float c0 = scos[il][ln], c1 = scos[il][ln + 64];
        float b0 = mA * smB[ln], b1 = mA * smB[ln + 64];
        float sc = c0 + c1;
        float sm = c0 * b0 + c1 * b1;
        float cn = b0 + b1;
        float mm = fmaxf(b0, b1);
        float vm = fmaxf(b0 > 0.f ? c0 : MINV, b1 > 0.f ? c1 : MINV);
        for (int d = 1; d < 64; d <<= 1) {
            sc += __shfl_xor(sc, d);
            sm += __shfl_xor(sm, d);
            cn += __shfl_xor(cn, d);
            mm = fmaxf(mm, __shfl_xor(mm, d));
            vm = fmaxf(vm, __shfl_xor(vm, d));
        }
        if (ln == 0) {
            float* orow = outBase + (size_t)gi * C;
            orow[0] = vm * mm;          // cos_max (MIN_VAL*0 -> -0 matches ref)
            orow[1] = sm / fmaxf(cn, EPSF);
        }
        // fused attentive mean/max: lane ln -> k = {2ln, 2ln+1}, ln < 50
        if (ln < 50) {
            float am0 = 0.f, am1 = 0.f, ax0 = MINV, ax1 = MINV;
            const u32* bvp = (const u32*)sBv + ln;       // dword ln of row j
            #pragma unroll 4
            for (int j = 0; j < L; ++j) {
                u32 pk = bvp[(size_t)j * 64];
                float bv0 = __uint_as_float(pk << 16);
                float bv1 = __uint_as_float(pk & 0xffff0000u);
                float cj = scos[il][j];
                bool mj = smB[j] > 0.f;
                float v0 = cj * bv0, v1 = cj * bv1;
                am0 += v0; am1 += v1;
                ax0 = fmaxf(ax0, mj ? v0 : MINV);
                ax1 = fmaxf(ax1, mj ? v1 : MINV);
            }
            const float rs = __builtin_amdgcn_rcpf(fmaxf(sc, EPSF));
            float2 vam = {am0 * rs, am1 * rs};
            float2 vax = {ax0 * mm, ax1 * mm};
            *(float2*)&sam[il][2 * ln] = vam;
            *(float2*)&sax[il][2 * ln] = vax;
        }
    }
    __syncthreads();

    // ---- phase 3: channel dots. task -> (row il, channel c in [0,63))
    for (int task = t; task < TI * 63; task += 256) {
        const int il = task / 63, c = task - il * 63;
        float* orow = outBase + (size_t)(i0 + il) * C;
        const float4* a4 = (const float4*)sa[il];
        if (c < 60) {
            const int grp = c / 20, p = c - grp * 20;
            const float* wrow = (grp == 0 ? w0 : grp == 1 ? w2 : w3) + p * H;
            const float* oth = grp == 0 ? sl : grp == 1 ? sam[il] : sax[il];
            const float4* w4 = (const float4*)wrow;
            const float4* o4 = (const float4*)oth;
            float d = 0.f, na = 0.f, nb = 0.f;
            #pragma unroll 5
            for (int k = 0; k < H / 4; ++k) {
                float4 w = w4[k], a = a4[k], o = o4[k];
                float ww;
                ww = w.x * w.x; d += ww * a.x * o.x; na += ww * a.x * a.x; nb += ww * o.x * o.x;
                ww = w.y * w.y; d += ww * a.y * o.y; na += ww * a.y * a.y; nb += ww * o.y * o.y;
                ww = w.z * w.z; d += ww * a.z * o.z; na += ww * a.z * a.z; nb += ww * o.z * o.z;
                ww = w.w * w.w; d += ww * a.w * o.w; na += ww * a.w * a.w; nb += ww * o.w * o.w;
            }
            const int base = (grp == 0) ? 3 : (grp == 1) ? 64 : 85;
            orow[base + p] = d / (fmaxf(sqrtf(na), EPSF) * fmaxf(sqrtf(nb), EPSF));
        } else {
            const float* oth = (c == 60) ? sl : (c == 61) ? sam[il] : sax[il];
            const float4* o4 = (const float4*)oth;
            float d = 0.f, na = 0.f, nb = 0.f;
            #pragma unroll 5
            for (int k = 0; k < H / 4; ++k) {
                float4 a = a4[k], o = o4[k];
                d += a.x * o.x + a.y * o.y + a.z * o.z + a.w * o.w;
                na += a.x * a.x + a.y * a.y + a.z * a.z + a.w * a.w;
                nb += o.x * o.x + o.y * o.y + o.z * o.z + o.w * o.w;
            }
            orow[(c == 60) ? 2 : (c == 61) ? 63 : 84] =
                d / (fmaxf(sqrtf(na), EPSF) * fmaxf(sqrtf(nb), EPSF));
        }
    }
}

// ---------------------------------------------------------------- launch
extern "C" void kernel_launch(void* const* d_in, const int* in_sizes, int n_in,
                              void* d_out, int out_size, void* d_ws, size_t ws_size,
                              hipStream_t stream)
{
    const float* ctx_p = (const float*)d_in[0];
    const int*   mask_p = (const int*)d_in[1];
    const float* ctx_h = (const float*)d_in[2];
    const int*   mask_h = (const int*)d_in[3];
    const float* w0 = (const float*)d_in[4];
    const float* w1 = (const float*)d_in[5];
    const float* w2 = (const float*)d_in[6];
    const float* w3 = (const float*)d_in[7];
    float* out = (float*)d_out;

    float* ws   = (float*)d_ws;
    float* cp   = ws;                       // B*L*H
    float* ch   = cp   + B * L * H;
    float* np_  = ch   + B * L * H;         // B*L
    float* nh_  = np_  + B * L;
    float* nw1p = nh_  + B * L;             // B*L*P
    float* nw1h = nw1p + B * L * P;
    float* cosM = nw1h + B * L * P;         // B*L*L
    float* cosT = cosM + B * L * L;         // B*L*L
    u16*   cpb  = (u16*)(cosT + B * L * L); // B*L*128 u16
    u16*   chb  = cpb + B * L * 128;

    float* out_h = out + B * L * C;

    k_prep<<<dim3(L, B, 2), dim3(128), 0, stream>>>(
        ctx_p, mask_p, ctx_h, mask_h, w1,
        cp, ch, cpb, chb, np_, nh_, nw1p, nw1h);
    k_pair_mfma<<<dim3(P + 1, B), dim3(256), 0, stream>>>(
        cpb, chb, w1, nw1p, nw1h, np_, nh_, mask_p, mask_h,
        out, out_h, cosM, cosT);
    k_side_t<<<dim3(L / TI, B, 2), dim3(256), 0, stream>>>(
        cp, ch, cpb, chb, cosM, cosT, mask_p, mask_h, w0, w2, w3, out);
}

// Round 6
// 138.908 us; speedup vs baseline: 1.6849x; 1.0727x over previous
//
#include <hip/hip_runtime.h>
#include <math.h>

// MatchingLayer (BiMPM-style) — MI355X. Round 6: compact-valid-j attentive
// loop, cos scalars moved into the MFMA cos block, restructured k_prep norms.
// B=32, L=128, H=100, P=20, C=105.

namespace {
constexpr int B = 32;
constexpr int L = 128;
constexpr int H = 100;
constexpr int P = 20;
constexpr int C = 105;
constexpr int TI = 8;          // i-rows per k_side block
constexpr float EPSF = 1e-8f;
constexpr float MINV = -1e7f;
}

typedef unsigned short u16;
typedef unsigned int u32;
typedef short sh8 __attribute__((ext_vector_type(8)));   // 8 bf16 (4 VGPRs)
typedef float f4 __attribute__((ext_vector_type(4)));

__device__ __forceinline__ u16 f2bf(float f) {           // RNE f32->bf16
    u32 u = __float_as_uint(f);
    u += 0x7FFFu + ((u >> 16) & 1u);
    return (u16)(u >> 16);
}
__device__ __forceinline__ float bf2f(u32 h) {
    return __uint_as_float(h << 16);
}

// ---------------------------------------------------------------- k_prep
// grid (L,B,2), block 128. Masked vector (fp32 + bf16 K=128 padded copy),
// plain norm + P w1-weighted norms via 5-lane K-split (105 active lanes).
__global__ void k_prep(const float* __restrict__ ctx_p, const int* __restrict__ mask_p,
                       const float* __restrict__ ctx_h, const int* __restrict__ mask_h,
                       const float* __restrict__ w1,
                       float* __restrict__ cp, float* __restrict__ ch,
                       u16* __restrict__ cpb, u16* __restrict__ chb,
                       float* __restrict__ np_, float* __restrict__ nh_,
                       float* __restrict__ nwp, float* __restrict__ nwh)
{
    const int b = blockIdx.y, i = blockIdx.x, side = blockIdx.z, t = threadIdx.x;
    const float* ctx = side ? ctx_h : ctx_p;
    const int*  mask = side ? mask_h : mask_p;
    float* dst  = side ? ch  : cp;
    u16*   dstb = side ? chb : cpb;
    float* nrm  = side ? nh_ : np_;
    float* nw   = side ? nwh : nwp;

    const int row = b * L + i;
    __shared__ __align__(16) float sv2[H];
    const float m = (float)mask[row];
    float v = 0.f;
    if (t < H) {
        v = ctx[row * H + t] * m;
        dst[row * H + t] = v;
        sv2[t] = v * v;
    }
    dstb[row * 128 + t] = f2bf(v);   // zero pad for t>=H
    __syncthreads();

    // 21 norm tasks (20 weighted + 1 plain), each split over 5 lanes.
    const int w = t >> 6, ln = t & 63;
    int g = -1, seg = 0;
    if (w == 0) { if (ln < 60) { g = ln / 5; seg = ln % 5; } }
    else        { if (ln < 45) { g = 12 + ln / 5; seg = ln % 5; } }
    if (g >= 0) {
        const float4* v4 = (const float4*)sv2;
        float acc = 0.f;
        if (g < P) {
            const float4* w4 = (const float4*)(w1 + g * H);
            #pragma unroll
            for (int k = seg * 5; k < seg * 5 + 5; ++k) {
                float4 wv_ = w4[k], s = v4[k];
                acc += wv_.x * wv_.x * s.x + wv_.y * wv_.y * s.y +
                       wv_.z * wv_.z * s.z + wv_.w * wv_.w * s.w;
            }
        } else {
            #pragma unroll
            for (int k = seg * 5; k < seg * 5 + 5; ++k) {
                float4 s = v4[k];
                acc += s.x + s.y + s.z + s.w;
            }
        }
        float a1 = __shfl(acc, ln + 1), a2 = __shfl(acc, ln + 2);
        float a3 = __shfl(acc, ln + 3), a4 = __shfl(acc, ln + 4);
        if (seg == 0) {
            float s = acc + a1 + a2 + a3 + a4;
            if (g < P) nw[row * P + g] = sqrtf(s);
            else       nrm[row] = sqrtf(s);
        }
    }
}

// ---------------------------------------------------------------- k_pair_mfma
// grid (P+1, B), 256 thr. p<20: w1^2-weighted 128x128x128 bf16 GEMM + masked
// max/mean pooling (ch 23+p / 43+p both sides). p==20: identity weights ->
// cosine matrix: writes cosM/cosT, pooled ch 0/1 both sides, and unmasked
// row/col cos sums (scP/scH) for the attentive-mean denominators.
__global__ __launch_bounds__(256) void
k_pair_mfma(const u16* __restrict__ Ab, const u16* __restrict__ Bb,
            const float* __restrict__ w1,
            const float* __restrict__ nwA, const float* __restrict__ nwB,
            const float* __restrict__ np_, const float* __restrict__ nh_,
            const int* __restrict__ maskA, const int* __restrict__ maskB,
            float* __restrict__ outP, float* __restrict__ outH,
            float* __restrict__ cosM, float* __restrict__ cosT,
            float* __restrict__ scP, float* __restrict__ scH)
{
    const int p = blockIdx.x, b = blockIdx.y, t = threadIdx.x;
    const bool is_cos = (p == P);
    __shared__ __align__(16) u16 sB[128 * 136];
    __shared__ float snwA[128], snwB[128], smA[128], smB[128];
    __shared__ float pJmax[128], pJsum[128], pJall[128];
    __shared__ float pImax[4][128], pIsum[4][128], pIall[4][128];
    __shared__ float sRed[4];                          // maxA,sumA,maxB,sumB

    if (t < 128) {
        snwA[t] = is_cos ? np_[b * L + t] : nwA[(b * L + t) * P + p];
        snwB[t] = is_cos ? nh_[b * L + t] : nwB[(b * L + t) * P + p];
        smA[t] = (float)maskA[b * L + t];
        smB[t] = (float)maskB[b * L + t];
    }
    __syncthreads();

    if (t < 64) {
        float a0 = smB[t], a1 = smB[t + 64];
        float mx = fmaxf(a0, a1), sm = a0 + a1;
        for (int d = 1; d < 64; d <<= 1) {
            mx = fmaxf(mx, __shfl_xor(mx, d));
            sm += __shfl_xor(sm, d);
        }
        if (t == 0) { sRed[2] = mx; sRed[3] = sm; }
    } else if (t < 128) {
        const int l = t - 64;
        float a0 = smA[l], a1 = smA[l + 64];
        float mx = fmaxf(a0, a1), sm = a0 + a1;
        for (int d = 1; d < 64; d <<= 1) {
            mx = fmaxf(mx, __shfl_xor(mx, d));
            sm += __shfl_xor(sm, d);
        }
        if (l == 0) { sRed[0] = mx; sRed[1] = sm; }
    }

    {   // stage B into LDS (bf16, K already zero-padded)
        const uint4* src = (const uint4*)(Bb + (size_t)b * L * 128);
        #pragma unroll
        for (int it = 0; it < 8; ++it) {
            int idx = it * 256 + t;
            int row = idx >> 4, kc = (idx & 15) * 8;
            uint4 v = src[idx];
            *(uint4*)&sB[row * 136 + kc] = v;
        }
    }
    __syncthreads();

    const int wave = t >> 6, lane = t & 63;
    const int m = lane & 15, q = lane >> 4;

    // weights^2 for this lane's k positions (identity for the cos block)
    float swv[4][8];
    #pragma unroll
    for (int ks = 0; ks < 4; ++ks)
        #pragma unroll
        for (int e = 0; e < 8; ++e) {
            int k = ks * 32 + q * 8 + e;
            if (is_cos) swv[ks][e] = (k < H) ? 1.f : 0.f;
            else {
                float w = (k < H) ? w1[p * H + k] : 0.f;
                swv[ks][e] = w * w;
            }
        }

    f4 acc[2][8];
    #pragma unroll
    for (int rt = 0; rt < 2; ++rt)
        #pragma unroll
        for (int ct = 0; ct < 8; ++ct)
            acc[rt][ct] = (f4){0.f, 0.f, 0.f, 0.f};

    const uint4* gA0 = (const uint4*)(Ab + (size_t)(b * L + wave * 32 + m) * 128);
    const uint4* gA1 = (const uint4*)(Ab + (size_t)(b * L + wave * 32 + 16 + m) * 128);

    #pragma unroll
    for (int ks = 0; ks < 4; ++ks) {
        uint4 va0 = gA0[ks * 4 + q];
        uint4 va1 = gA1[ks * 4 + q];
        sh8 a0, a1;
        {
            u32 vs0[4] = {va0.x, va0.y, va0.z, va0.w};
            u32 vs1[4] = {va1.x, va1.y, va1.z, va1.w};
            u32 r0[4], r1[4];
            #pragma unroll
            for (int e = 0; e < 4; ++e) {
                float f0 = bf2f(vs0[e] & 0xffffu) * swv[ks][2 * e];
                float f1 = bf2f(vs0[e] >> 16) * swv[ks][2 * e + 1];
                r0[e] = (u32)f2bf(f0) | ((u32)f2bf(f1) << 16);
                float g0 = bf2f(vs1[e] & 0xffffu) * swv[ks][2 * e];
                float g1 = bf2f(vs1[e] >> 16) * swv[ks][2 * e + 1];
                r1[e] = (u32)f2bf(g0) | ((u32)f2bf(g1) << 16);
            }
            uint4 o0 = {r0[0], r0[1], r0[2], r0[3]};
            uint4 o1 = {r1[0], r1[1], r1[2], r1[3]};
            a0 = __builtin_bit_cast(sh8, o0);
            a1 = __builtin_bit_cast(sh8, o1);
        }
        const int ko = ks * 32 + q * 8;
        #pragma unroll
        for (int ct = 0; ct < 8; ++ct) {
            sh8 bb = *(const sh8*)&sB[(ct * 16 + m) * 136 + ko];
            acc[0][ct] = __builtin_amdgcn_mfma_f32_16x16x32_bf16(a0, bb, acc[0][ct], 0, 0, 0);
            acc[1][ct] = __builtin_amdgcn_mfma_f32_16x16x32_bf16(a1, bb, acc[1][ct], 0, 0, 0);
        }
    }

    // unified epilogue: mv = acc / max(nA*nB, eps); pool over j and i.
    // cos block additionally stores cosM/cosT and unmasked row/col sums.
    float nB[8], mBv[8], imax[8], isum[8], iall[8];
    #pragma unroll
    for (int ct = 0; ct < 8; ++ct) {
        const int j = ct * 16 + m;
        nB[ct] = snwB[j]; mBv[ct] = smB[j];
        imax[ct] = MINV; isum[ct] = 0.f; iall[ct] = 0.f;
    }
    #pragma unroll
    for (int rt = 0; rt < 2; ++rt) {
        #pragma unroll
        for (int reg = 0; reg < 4; ++reg) {
            const int i = wave * 32 + rt * 16 + q * 4 + reg;
            const float na = snwA[i];
            const float ma = smA[i];
            float jmax = MINV, jsum = 0.f, jall = 0.f;
            #pragma unroll
            for (int ct = 0; ct < 8; ++ct) {
                float v = acc[rt][ct][reg] *
                          __builtin_amdgcn_rcpf(fmaxf(na * nB[ct], EPSF));
                if (is_cos) {
                    const int j = ct * 16 + m;
                    cosM[((size_t)b * L + i) * L + j] = v;
                    cosT[((size_t)b * L + j) * L + i] = v;
                    jall += v;
                    iall[ct] += v;
                }
                jmax = fmaxf(jmax, mBv[ct] > 0.f ? v : MINV);
                jsum += mBv[ct] > 0.f ? v : 0.f;
                imax[ct] = fmaxf(imax[ct], ma > 0.f ? v : MINV);
                isum[ct] += ma > 0.f ? v : 0.f;
            }
            for (int d = 1; d < 16; d <<= 1) {
                jmax = fmaxf(jmax, __shfl_xor(jmax, d));
                jsum += __shfl_xor(jsum, d);
                if (is_cos) jall += __shfl_xor(jall, d);
            }
            if (m == 0) { pJmax[i] = jmax; pJsum[i] = jsum; if (is_cos) pJall[i] = jall; }
        }
    }
    #pragma unroll
    for (int ct = 0; ct < 8; ++ct) {
        float mx = imax[ct], sm = isum[ct], al = iall[ct];
        mx = fmaxf(mx, __shfl_xor(mx, 16)); sm += __shfl_xor(sm, 16);
        mx = fmaxf(mx, __shfl_xor(mx, 32)); sm += __shfl_xor(sm, 32);
        if (is_cos) { al += __shfl_xor(al, 16); al += __shfl_xor(al, 32); }
        if (q == 0) {
            const int j = ct * 16 + m;
            pImax[wave][j] = mx; pIsum[wave][j] = sm;
            if (is_cos) pIall[wave][j] = al;
        }
    }
    __syncthreads();

    if (t < 128) {
        const int i = t;
        const int co0 = is_cos ? 0 : 23 + p;
        const int co1 = is_cos ? 1 : 43 + p;
        const float ma = smA[i];
        const float mm = ma * sRed[2];
        const float cnt = ma * sRed[3];
        float* orow = outP + ((size_t)b * L + i) * C;
        orow[co0] = pJmax[i] * mm;
        orow[co1] = ma * pJsum[i] / fmaxf(cnt, EPSF);

        const float mb = smB[i];
        const float hmax = fmaxf(fmaxf(pImax[0][i], pImax[1][i]),
                                 fmaxf(pImax[2][i], pImax[3][i]));
        const float hsum = pIsum[0][i] + pIsum[1][i] + pIsum[2][i] + pIsum[3][i];
        float* hrow = outH + ((size_t)b * L + i) * C;
        hrow[co0] = hmax * mb * sRed[0];
        hrow[co1] = mb * hsum / fmaxf(mb * sRed[1], EPSF);

        if (is_cos) {
            scP[b * L + i] = pJall[i];
            scH[b * L + i] = pIall[0][i] + pIall[1][i] + pIall[2][i] + pIall[3][i];
        }
    }
}

// ---------------------------------------------------------------- k_side_t
// grid (L/TI, B, 2), block 256. Compact valid-j list via ballot; stage only
// valid Bv rows (bf16) + compact cos; attentive loop has no mask tests.
// Phase 3: 504 channel-dot tasks over all threads.
__global__ __launch_bounds__(256, 3) void
k_side_t(const float* __restrict__ cp, const float* __restrict__ ch,
         const u16* __restrict__ cpb, const u16* __restrict__ chb,
         const float* __restrict__ cosM, const float* __restrict__ cosT,
         const float* __restrict__ scP, const float* __restrict__ scH,
         const int* __restrict__ mask_p, const int* __restrict__ mask_h,
         const float* __restrict__ w0, const float* __restrict__ w2,
         const float* __restrict__ w3, float* __restrict__ out)
{
    const int tile = blockIdx.x, b = blockIdx.y, side = blockIdx.z, t = threadIdx.x;
    const int i0 = tile * TI;
    const float* A   = side ? ch : cp;
    const float* Bv  = side ? cp : ch;
    const u16*  Bvb  = side ? cpb : chb;
    const int* maskA = side ? mask_h : mask_p;
    const int* maskB = side ? mask_p : mask_h;
    const float* cosSrc = side ? cosT : cosM;
    const float* scArr  = side ? scH : scP;
    float* outBase = out + ((size_t)side * B * L + (size_t)b * L) * C;

    __shared__ __align__(16) u16  sBvC[128 * 128];       // 32 KB compact rows
    __shared__ float scosC[TI][128];                     // 4 KB compact cos
    __shared__ __align__(16) float sa[TI][H];            // 3.2 KB
    __shared__ __align__(16) float sam[TI][H];           // 3.2 KB
    __shared__ __align__(16) float sax[TI][H];           // 3.2 KB
    __shared__ __align__(16) float sl[H];                // 0.4 KB
    __shared__ u16 cidx[128];
    __shared__ int snv;

    const int wv = t >> 6, ln = t & 63;

    // ---- phase 0: valid-j list (wave 0) + A-row staging (waves 2-3)
    if (wv == 0) {
        int m0 = maskB[b * L + ln], m1 = maskB[b * L + 64 + ln];
        unsigned long long b0 = __ballot(m0 > 0);
        unsigned long long b1 = __ballot(m1 > 0);
        unsigned long long pre = (1ull << ln) - 1ull;
        int n0 = __popcll(b0);
        if (m0 > 0) cidx[__popcll(b0 & pre)] = (u16)ln;
        if (m1 > 0) cidx[n0 + __popcll(b1 & pre)] = (u16)(64 + ln);
        if (ln == 0) snv = n0 + __popcll(b1);
    } else if (wv >= 2) {
        for (int x = t - 128; x < TI * 128; x += 128) {
            int il = x >> 7, k = x & 127;
            if (k < H) sa[il][k] = A[((size_t)b * L + i0 + il) * H + k];
        }
    }
    __syncthreads();
    const int nv = snv;

    // ---- phase 1: stage compact Bv rows (bf16) + compact cos; wave1: sl
    {
        const uint4* src = (const uint4*)(Bvb + (size_t)b * L * 128);
        uint4* dst = (uint4*)sBvC;
        for (int c = t; c < nv * 16; c += 256) {
            int jj = c >> 4, cc = c & 15;
            dst[c] = src[(int)cidx[jj] * 16 + cc];
        }
        for (int x = t; x < TI * 128; x += 256) {
            int il = x >> 7, jj = x & 127;
            if (jj < nv)
                scosC[il][jj] = cosSrc[((size_t)b * L + i0 + il) * L + cidx[jj]];
        }
        if (wv == 1) {
            int last = nv - 1; if (last < 0) last = 0;
            const float* lr = Bv + ((size_t)b * L + last) * H;
            sl[ln] = lr[ln];
            if (ln + 64 < H) sl[ln + 64] = lr[ln + 64];
        }
    }
    __syncthreads();

    // ---- phase 2: wave wv owns rows wv and wv+4; lane -> k = {2ln, 2ln+1}
    #pragma unroll
    for (int pass = 0; pass < 2; ++pass) {
        const int il = wv + pass * 4;
        const int gi = i0 + il;
        if (ln < 50) {
            const float mA = (float)maskA[b * L + gi];
            const float sc = scArr[b * L + gi];
            float am0 = 0.f, am1 = 0.f, ax0 = MINV, ax1 = MINV;
            const u32* bp = (const u32*)sBvC + ln;
            const float* cr = scosC[il];
            #pragma unroll 4
            for (int jj = 0; jj < nv; ++jj) {
                u32 pk = bp[jj * 64];
                float cj = cr[jj];
                float v0 = cj * __uint_as_float(pk << 16);
                float v1 = cj * __uint_as_float(pk & 0xffff0000u);
                am0 += v0; am1 += v1;
                ax0 = fmaxf(ax0, v0); ax1 = fmaxf(ax1, v1);
            }
            const float rs = __builtin_amdgcn_rcpf(fmaxf(sc, EPSF));
            const float mm = (nv > 0) ? mA : 0.f;
            sam[il][2 * ln] = am0 * rs; sam[il][2 * ln + 1] = am1 * rs;
            sax[il][2 * ln] = ax0 * mm; sax[il][2 * ln + 1] = ax1 * mm;
        }
    }
    __syncthreads();

    // ---- phase 3: channel dots. task -> (row il, channel c in [0,63))
    for (int task = t; task < TI * 63; task += 256) {
        const int il = task / 63, c = task - il * 63;
        float* orow = outBase + (size_t)(i0 + il) * C;
        const float4* a4 = (const float4*)sa[il];
        if (c < 60) {
            const int grp = c / 20, p = c - grp * 20;
            const float* wrow = (grp == 0 ? w0 : grp == 1 ? w2 : w3) + p * H;
            const float* oth = grp == 0 ? sl : grp == 1 ? sam[il] : sax[il];
            const float4* w4 = (const float4*)wrow;
            const float4* o4 = (const float4*)oth;
            float d = 0.f, na = 0.f, nb = 0.f;
            #pragma unroll 5
            for (int k = 0; k < H / 4; ++k) {
                float4 w = w4[k], a = a4[k], o = o4[k];
                float ww;
                ww = w.x * w.x; d += ww * a.x * o.x; na += ww * a.x * a.x; nb += ww * o.x * o.x;
                ww = w.y * w.y; d += ww * a.y * o.y; na += ww * a.y * a.y; nb += ww * o.y * o.y;
                ww = w.z * w.z; d += ww * a.z * o.z; na += ww * a.z * a.z; nb += ww * o.z * o.z;
                ww = w.w * w.w; d += ww * a.w * o.w; na += ww * a.w * a.w; nb += ww * o.w * o.w;
            }
            const int base = (grp == 0) ? 3 : (grp == 1) ? 64 : 85;
            orow[base + p] = d / (fmaxf(sqrtf(na), EPSF) * fmaxf(sqrtf(nb), EPSF));
        } else {
            const float* oth = (c == 60) ? sl : (c == 61) ? sam[il] : sax[il];
            const float4* o4 = (const float4*)oth;
            float d = 0.f, na = 0.f, nb = 0.f;
            #pragma unroll 5
            for (int k = 0; k < H / 4; ++k) {
                float4 a = a4[k], o = o4[k];
                d += a.x * o.x + a.y * o.y + a.z * o.z + a.w * o.w;
                na += a.x * a.x + a.y * a.y + a.z * a.z + a.w * a.w;
                nb += o.x * o.x + o.y * o.y + o.z * o.z + o.w * o.w;
            }
            orow[(c == 60) ? 2 : (c == 61) ? 63 : 84] =
                d / (fmaxf(sqrtf(na), EPSF) * fmaxf(sqrtf(nb), EPSF));
        }
    }
}

// ---------------------------------------------------------------- launch
extern "C" void kernel_launch(void* const* d_in, const int* in_sizes, int n_in,
                              void* d_out, int out_size, void* d_ws, size_t ws_size,
                              hipStream_t stream)
{
    const float* ctx_p = (const float*)d_in[0];
    const int*   mask_p = (const int*)d_in[1];
    const float* ctx_h = (const float*)d_in[2];
    const int*   mask_h = (const int*)d_in[3];
    const float* w0 = (const float*)d_in[4];
    const float* w1 = (const float*)d_in[5];
    const float* w2 = (const float*)d_in[6];
    const float* w3 = (const float*)d_in[7];
    float* out = (float*)d_out;

    float* ws   = (float*)d_ws;
    float* cp   = ws;                       // B*L*H
    float* ch   = cp   + B * L * H;
    float* np_  = ch   + B * L * H;         // B*L
    float* nh_  = np_  + B * L;
    float* nw1p = nh_  + B * L;             // B*L*P
    float* nw1h = nw1p + B * L * P;
    float* cosM = nw1h + B * L * P;         // B*L*L
    float* cosT = cosM + B * L * L;         // B*L*L
    float* scP  = cosT + B * L * L;         // B*L
    float* scH  = scP  + B * L;
    u16*   cpb  = (u16*)(scH + B * L);      // B*L*128 u16
    u16*   chb  = cpb + B * L * 128;

    float* out_h = out + B * L * C;

    k_prep<<<dim3(L, B, 2), dim3(128), 0, stream>>>(
        ctx_p, mask_p, ctx_h, mask_h, w1,
        cp, ch, cpb, chb, np_, nh_, nw1p, nw1h);
    k_pair_mfma<<<dim3(P + 1, B), dim3(256), 0, stream>>>(
        cpb, chb, w1, nw1p, nw1h, np_, nh_, mask_p, mask_h,
        out, out_h, cosM, cosT, scP, scH);
    k_side_t<<<dim3(L / TI, B, 2), dim3(256), 0, stream>>>(
        cp, ch, cpb, chb, cosM, cosT, scP, scH,
        mask_p, mask_h, w0, w2, w3, out);
}

// Round 8
// 136.682 us; speedup vs baseline: 1.7123x; 1.0163x over previous
//
#include <hip/hip_runtime.h>
#include <math.h>

// MatchingLayer (BiMPM-style) — MI355X. Round 8: round-7 fused structure with
// the side-path LDS staging bound fixed (nct*256 uint4s, not nct*16).
// Grid (20+32, B): x<20 -> pair-GEMM blocks (MFMA), x>=20 -> side tiles that
// compute their own cos tile via MFMA (bf16 A rows already in cpb/chb).
// B=32, L=128, H=100, P=20, C=105.

namespace {
constexpr int B = 32;
constexpr int L = 128;
constexpr int H = 100;
constexpr int P = 20;
constexpr int C = 105;
constexpr int TI = 8;            // i-rows per side tile
constexpr int SMEM_BYTES = 50176;
constexpr float EPSF = 1e-8f;
constexpr float MINV = -1e7f;
}

typedef unsigned short u16;
typedef unsigned int u32;
typedef short sh8 __attribute__((ext_vector_type(8)));   // 8 bf16 (4 VGPRs)
typedef float f4 __attribute__((ext_vector_type(4)));

__device__ __forceinline__ u16 f2bf(float f) {           // RNE f32->bf16
    u32 u = __float_as_uint(f);
    u += 0x7FFFu + ((u >> 16) & 1u);
    return (u16)(u >> 16);
}
__device__ __forceinline__ float bf2f(u32 h) {
    return __uint_as_float(h << 16);
}

// ---------------------------------------------------------------- k_prep
// grid (L,B,2), block 128. Masked vector (fp32 + bf16 K=128 padded copy),
// plain norm + P w1-weighted norms via 5-lane K-split (105 active lanes).
__global__ void k_prep(const float* __restrict__ ctx_p, const int* __restrict__ mask_p,
                       const float* __restrict__ ctx_h, const int* __restrict__ mask_h,
                       const float* __restrict__ w1,
                       float* __restrict__ cp, float* __restrict__ ch,
                       u16* __restrict__ cpb, u16* __restrict__ chb,
                       float* __restrict__ np_, float* __restrict__ nh_,
                       float* __restrict__ nwp, float* __restrict__ nwh)
{
    const int b = blockIdx.y, i = blockIdx.x, side = blockIdx.z, t = threadIdx.x;
    const float* ctx = side ? ctx_h : ctx_p;
    const int*  mask = side ? mask_h : mask_p;
    float* dst  = side ? ch  : cp;
    u16*   dstb = side ? chb : cpb;
    float* nrm  = side ? nh_ : np_;
    float* nw   = side ? nwh : nwp;

    const int row = b * L + i;
    __shared__ __align__(16) float sv2[H];
    const float m = (float)mask[row];
    float v = 0.f;
    if (t < H) {
        v = ctx[row * H + t] * m;
        dst[row * H + t] = v;
        sv2[t] = v * v;
    }
    dstb[row * 128 + t] = f2bf(v);   // zero pad for t>=H
    __syncthreads();

    const int w = t >> 6, ln = t & 63;
    int g = -1, seg = 0;
    if (w == 0) { if (ln < 60) { g = ln / 5; seg = ln % 5; } }
    else        { if (ln < 45) { g = 12 + ln / 5; seg = ln % 5; } }
    if (g >= 0) {
        const float4* v4 = (const float4*)sv2;
        float acc = 0.f;
        if (g < P) {
            const float4* w4 = (const float4*)(w1 + g * H);
            #pragma unroll
            for (int k = seg * 5; k < seg * 5 + 5; ++k) {
                float4 wv_ = w4[k], s = v4[k];
                acc += wv_.x * wv_.x * s.x + wv_.y * wv_.y * s.y +
                       wv_.z * wv_.z * s.z + wv_.w * wv_.w * s.w;
            }
        } else {
            #pragma unroll
            for (int k = seg * 5; k < seg * 5 + 5; ++k) {
                float4 s = v4[k];
                acc += s.x + s.y + s.z + s.w;
            }
        }
        float a1 = __shfl(acc, ln + 1), a2 = __shfl(acc, ln + 2);
        float a3 = __shfl(acc, ln + 3), a4 = __shfl(acc, ln + 4);
        if (seg == 0) {
            float s = acc + a1 + a2 + a3 + a4;
            if (g < P) nw[row * P + g] = sqrtf(s);
            else       nrm[row] = sqrtf(s);
        }
    }
}

// ---------------------------------------------------------------- k_main
// One dispatch. bx<P: pair GEMM for p=bx (both sides' ch 23+p/43+p).
// bx>=P: side tile (side=(bx-P)>>4, tile=(bx-P)&15): self-contained cos via
// MFMA + attentive mean/max + all remaining channels for 8 rows.
__global__ __launch_bounds__(256) void
k_main(const float* __restrict__ cp, const float* __restrict__ ch,
       const u16* __restrict__ cpb, const u16* __restrict__ chb,
       const float* __restrict__ np_, const float* __restrict__ nh_,
       const float* __restrict__ nw1p, const float* __restrict__ nw1h,
       const int* __restrict__ mask_p, const int* __restrict__ mask_h,
       const float* __restrict__ w0, const float* __restrict__ w1,
       const float* __restrict__ w2, const float* __restrict__ w3,
       float* __restrict__ out)
{
    __shared__ __align__(16) char smem[SMEM_BYTES];
    const int bx = blockIdx.x, b = blockIdx.y, t = threadIdx.x;
    const int wv = t >> 6, ln = t & 63;
    float* out_p = out;
    float* out_h = out + (size_t)B * L * C;

    if (bx < P) {
        // ==================== pair path ====================
        const int p = bx;
        u16*  sB    = (u16*)smem;                      // [128][136]
        float* snwA = (float*)(smem + 34816);
        float* snwB = (float*)(smem + 35328);
        float* smA  = (float*)(smem + 35840);
        float* smB  = (float*)(smem + 36352);
        float* pJmax= (float*)(smem + 36864);
        float* pJsum= (float*)(smem + 37376);
        float* pImax= (float*)(smem + 37888);          // [4][128]
        float* pIsum= (float*)(smem + 39936);          // [4][128]
        float* sRed = (float*)(smem + 41984);          // 4

        if (t < 128) {
            snwA[t] = nw1p[(b * L + t) * P + p];
            snwB[t] = nw1h[(b * L + t) * P + p];
            smA[t] = (float)mask_p[b * L + t];
            smB[t] = (float)mask_h[b * L + t];
        }
        __syncthreads();

        if (t < 64) {
            float a0 = smB[t], a1 = smB[t + 64];
            float mx = fmaxf(a0, a1), sm = a0 + a1;
            for (int d = 1; d < 64; d <<= 1) {
                mx = fmaxf(mx, __shfl_xor(mx, d));
                sm += __shfl_xor(sm, d);
            }
            if (t == 0) { sRed[2] = mx; sRed[3] = sm; }
        } else if (t < 128) {
            const int l = t - 64;
            float a0 = smA[l], a1 = smA[l + 64];
            float mx = fmaxf(a0, a1), sm = a0 + a1;
            for (int d = 1; d < 64; d <<= 1) {
                mx = fmaxf(mx, __shfl_xor(mx, d));
                sm += __shfl_xor(sm, d);
            }
            if (l == 0) { sRed[0] = mx; sRed[1] = sm; }
        }

        {   // stage B (h-side bf16 rows) into LDS, padded stride 136
            const uint4* src = (const uint4*)(chb + (size_t)b * L * 128);
            #pragma unroll
            for (int it = 0; it < 8; ++it) {
                int idx = it * 256 + t;
                int row = idx >> 4, kc = (idx & 15) * 8;
                uint4 v = src[idx];
                *(uint4*)&sB[row * 136 + kc] = v;
            }
        }
        __syncthreads();

        const int m = ln & 15, q = ln >> 4;

        float swv[4][8];
        #pragma unroll
        for (int ks = 0; ks < 4; ++ks)
            #pragma unroll
            for (int e = 0; e < 8; ++e) {
                int k = ks * 32 + q * 8 + e;
                float w = (k < H) ? w1[p * H + k] : 0.f;
                swv[ks][e] = w * w;
            }

        f4 acc[2][8];
        #pragma unroll
        for (int rt = 0; rt < 2; ++rt)
            #pragma unroll
            for (int ct = 0; ct < 8; ++ct)
                acc[rt][ct] = (f4){0.f, 0.f, 0.f, 0.f};

        const uint4* gA0 = (const uint4*)(cpb + (size_t)(b * L + wv * 32 + m) * 128);
        const uint4* gA1 = (const uint4*)(cpb + (size_t)(b * L + wv * 32 + 16 + m) * 128);

        #pragma unroll
        for (int ks = 0; ks < 4; ++ks) {
            uint4 va0 = gA0[ks * 4 + q];
            uint4 va1 = gA1[ks * 4 + q];
            sh8 a0, a1;
            {
                u32 vs0[4] = {va0.x, va0.y, va0.z, va0.w};
                u32 vs1[4] = {va1.x, va1.y, va1.z, va1.w};
                u32 r0[4], r1[4];
                #pragma unroll
                for (int e = 0; e < 4; ++e) {
                    float f0 = bf2f(vs0[e] & 0xffffu) * swv[ks][2 * e];
                    float f1 = bf2f(vs0[e] >> 16) * swv[ks][2 * e + 1];
                    r0[e] = (u32)f2bf(f0) | ((u32)f2bf(f1) << 16);
                    float g0 = bf2f(vs1[e] & 0xffffu) * swv[ks][2 * e];
                    float g1 = bf2f(vs1[e] >> 16) * swv[ks][2 * e + 1];
                    r1[e] = (u32)f2bf(g0) | ((u32)f2bf(g1) << 16);
                }
                uint4 o0 = {r0[0], r0[1], r0[2], r0[3]};
                uint4 o1 = {r1[0], r1[1], r1[2], r1[3]};
                a0 = __builtin_bit_cast(sh8, o0);
                a1 = __builtin_bit_cast(sh8, o1);
            }
            const int ko = ks * 32 + q * 8;
            #pragma unroll
            for (int ct = 0; ct < 8; ++ct) {
                sh8 bb = *(const sh8*)&sB[(ct * 16 + m) * 136 + ko];
                acc[0][ct] = __builtin_amdgcn_mfma_f32_16x16x32_bf16(a0, bb, acc[0][ct], 0, 0, 0);
                acc[1][ct] = __builtin_amdgcn_mfma_f32_16x16x32_bf16(a1, bb, acc[1][ct], 0, 0, 0);
            }
        }

        // epilogue: mv = acc / max(nwA*nwB, eps); pool over j and i
        float nB[8], mBv[8], imax[8], isum[8];
        #pragma unroll
        for (int ct = 0; ct < 8; ++ct) {
            const int j = ct * 16 + m;
            nB[ct] = snwB[j]; mBv[ct] = smB[j];
            imax[ct] = MINV; isum[ct] = 0.f;
        }
        #pragma unroll
        for (int rt = 0; rt < 2; ++rt) {
            #pragma unroll
            for (int reg = 0; reg < 4; ++reg) {
                const int i = wv * 32 + rt * 16 + q * 4 + reg;
                const float na = snwA[i];
                const float ma = smA[i];
                float jmax = MINV, jsum = 0.f;
                #pragma unroll
                for (int ct = 0; ct < 8; ++ct) {
                    float v = acc[rt][ct][reg] *
                              __builtin_amdgcn_rcpf(fmaxf(na * nB[ct], EPSF));
                    jmax = fmaxf(jmax, mBv[ct] > 0.f ? v : MINV);
                    jsum += mBv[ct] > 0.f ? v : 0.f;
                    imax[ct] = fmaxf(imax[ct], ma > 0.f ? v : MINV);
                    isum[ct] += ma > 0.f ? v : 0.f;
                }
                for (int d = 1; d < 16; d <<= 1) {
                    jmax = fmaxf(jmax, __shfl_xor(jmax, d));
                    jsum += __shfl_xor(jsum, d);
                }
                if (m == 0) { pJmax[i] = jmax; pJsum[i] = jsum; }
            }
        }
        #pragma unroll
        for (int ct = 0; ct < 8; ++ct) {
            float mx = imax[ct], sm = isum[ct];
            mx = fmaxf(mx, __shfl_xor(mx, 16)); sm += __shfl_xor(sm, 16);
            mx = fmaxf(mx, __shfl_xor(mx, 32)); sm += __shfl_xor(sm, 32);
            if (q == 0) { const int j = ct * 16 + m; pImax[wv * 128 + j] = mx; pIsum[wv * 128 + j] = sm; }
        }
        __syncthreads();

        if (t < 128) {
            const int i = t;
            const float ma = smA[i];
            const float mm = ma * sRed[2];
            const float cnt = ma * sRed[3];
            float* orow = out_p + ((size_t)b * L + i) * C;
            orow[23 + p] = pJmax[i] * mm;
            orow[43 + p] = ma * pJsum[i] / fmaxf(cnt, EPSF);

            const float mb = smB[i];
            const float hmax = fmaxf(fmaxf(pImax[0 * 128 + i], pImax[1 * 128 + i]),
                                     fmaxf(pImax[2 * 128 + i], pImax[3 * 128 + i]));
            const float hsum = pIsum[0 * 128 + i] + pIsum[1 * 128 + i] +
                               pIsum[2 * 128 + i] + pIsum[3 * 128 + i];
            float* hrow = out_h + ((size_t)b * L + i) * C;
            hrow[23 + p] = hmax * mb * sRed[0];
            hrow[43 + p] = mb * hsum / fmaxf(mb * sRed[1], EPSF);
        }
    } else {
        // ==================== side path ====================
        const int e = bx - P;
        const int side = e >> 4, tile = e & 15;
        const int i0 = tile * TI;
        const float* A   = side ? ch : cp;
        const float* Bv  = side ? cp : ch;
        const u16*  Ab16 = side ? chb : cpb;
        const u16*  Bvb  = side ? cpb : chb;
        const float* nA_ = side ? nh_ : np_;
        const float* nB_ = side ? np_ : nh_;
        const int* maskA = side ? mask_h : mask_p;
        const int* maskB = side ? mask_p : mask_h;
        float* outBase = out + ((size_t)side * B * L + (size_t)b * L) * C;

        // carve: sBvC u16[128][136] @0; scosC f[8][128] @34816; sa f[8][100]
        // @38912; sam @42112; sax @45312; sl f[100] @48512; snB f[128] @48912;
        // cidx u16[128] @49424; snA f[8] @49680; nv int @49712
        float* scosC = (float*)(smem + 34816);
        float* sa    = (float*)(smem + 38912);
        float* sam   = (float*)(smem + 42112);
        float* sax   = (float*)(smem + 45312);
        float* sl    = (float*)(smem + 48512);
        float* snB   = (float*)(smem + 48912);
        u16*  cidx  = (u16*)(smem + 49424);
        float* snA   = (float*)(smem + 49680);
        int*   pnv   = (int*)(smem + 49712);

        // ---- phase 0: valid-j list (wave 0) + A-row fp32 staging (waves 2-3)
        if (wv == 0) {
            int m0 = maskB[b * L + ln], m1 = maskB[b * L + 64 + ln];
            unsigned long long b0 = __ballot(m0 > 0);
            unsigned long long b1 = __ballot(m1 > 0);
            unsigned long long pre = (1ull << ln) - 1ull;
            int n0 = __popcll(b0);
            if (m0 > 0) cidx[__popcll(b0 & pre)] = (u16)ln;
            if (m1 > 0) cidx[n0 + __popcll(b1 & pre)] = (u16)(64 + ln);
            if (ln == 0) *pnv = n0 + __popcll(b1);
        } else if (wv >= 2) {
            for (int x = t - 128; x < TI * 128; x += 128) {
                int il = x >> 7, k = x & 127;
                if (k < H) sa[il * 100 + k] = A[((size_t)b * L + i0 + il) * H + k];
            }
        }
        __syncthreads();
        const int nv = *pnv;
        const int nct = (nv + 15) >> 4;

        // ---- phase 1: compact bf16 Bv rows (nct*16 rows x 16 uint4, padded
        //      stride 272 B; zero tail for jj>=nv) + norms + sl
        {
            const uint4* src = (const uint4*)(Bvb + (size_t)b * L * 128);
            for (int c = t; c < nct * 256; c += 256) {   // FIX: rows*16 uint4s
                int jj = c >> 4, cc = c & 15;
                uint4 v;
                if (jj < nv) v = src[(int)cidx[jj] * 16 + cc];
                else { v.x = v.y = v.z = v.w = 0u; }
                *(uint4*)(smem + jj * 272 + cc * 16) = v;
            }
            if (t < 128) snB[t] = (t < nv) ? nB_[b * L + (int)cidx[t]] : 0.f;
            else if (t < 136) snA[t - 128] = nA_[b * L + i0 + (t - 128)];
            if (wv == 1) {
                int last = nv - 1; if (last < 0) last = 0;    // ref: raw index sum-1
                const float* lr = Bv + ((size_t)b * L + last) * H;
                sl[ln] = lr[ln];
                if (ln + 64 < H) sl[ln + 64] = lr[ln + 64];
            }
        }
        __syncthreads();

        // ---- phase cos: 8x(nv) cos tile via MFMA; wave wv owns ct {wv, wv+4}
        const int m = ln & 15, q = ln >> 4;
        {
            const uint4* gA = (const uint4*)(Ab16 + (size_t)(b * L + i0 + (m & 7)) * 128);
            f4 acc0 = (f4){0.f, 0.f, 0.f, 0.f};
            f4 acc1 = (f4){0.f, 0.f, 0.f, 0.f};
            const int ct0 = wv, ct1 = wv + 4;
            #pragma unroll
            for (int ks = 0; ks < 4; ++ks) {
                uint4 va = gA[ks * 4 + q];
                if (m >= 8) { va.x = va.y = va.z = va.w = 0u; }
                sh8 af = __builtin_bit_cast(sh8, va);
                const int ko2 = (ks * 32 + q * 8) * 2;
                if (ct0 < nct) {
                    sh8 bb = *(const sh8*)(smem + (ct0 * 16 + m) * 272 + ko2);
                    acc0 = __builtin_amdgcn_mfma_f32_16x16x32_bf16(af, bb, acc0, 0, 0, 0);
                }
                if (ct1 < nct) {
                    sh8 bb = *(const sh8*)(smem + (ct1 * 16 + m) * 272 + ko2);
                    acc1 = __builtin_amdgcn_mfma_f32_16x16x32_bf16(af, bb, acc1, 0, 0, 0);
                }
            }
            if (q < 2) {
                #pragma unroll
                for (int reg = 0; reg < 4; ++reg) {
                    const int i = q * 4 + reg;
                    const float ni = snA[i];
                    if (ct0 < nct) {
                        const int jj = ct0 * 16 + m;
                        scosC[i * 128 + jj] = acc0[reg] *
                            __builtin_amdgcn_rcpf(fmaxf(ni * snB[jj], EPSF));
                    }
                    if (ct1 < nct) {
                        const int jj = ct1 * 16 + m;
                        scosC[i * 128 + jj] = acc1[reg] *
                            __builtin_amdgcn_rcpf(fmaxf(ni * snB[jj], EPSF));
                    }
                }
            }
        }
        __syncthreads();

        // ---- phase 2: wave wv rows {wv, wv+4}; lane -> k = {2ln, 2ln+1}
        #pragma unroll
        for (int pass = 0; pass < 2; ++pass) {
            const int il = wv + pass * 4;
            const int gi = i0 + il;
            if (ln < 50) {
                const float mA = (float)maskA[b * L + gi];
                float am0 = 0.f, am1 = 0.f, ax0 = MINV, ax1 = MINV;
                float scj = 0.f, cmx = MINV;
                const u32* bp = (const u32*)smem + ln;       // row stride 68 dwords
                const float* cr = scosC + il * 128;
                #pragma unroll 4
                for (int jj = 0; jj < nv; ++jj) {
                    u32 pk = bp[jj * 68];
                    float cj = cr[jj];
                    scj += cj; cmx = fmaxf(cmx, cj);
                    float v0 = cj * __uint_as_float(pk << 16);
                    float v1 = cj * __uint_as_float(pk & 0xffff0000u);
                    am0 += v0; am1 += v1;
                    ax0 = fmaxf(ax0, v0); ax1 = fmaxf(ax1, v1);
                }
                const float rs = __builtin_amdgcn_rcpf(fmaxf(scj, EPSF));
                const float mm = (nv > 0) ? mA : 0.f;
                sam[il * 100 + 2 * ln] = am0 * rs; sam[il * 100 + 2 * ln + 1] = am1 * rs;
                sax[il * 100 + 2 * ln] = ax0 * mm; sax[il * 100 + 2 * ln + 1] = ax1 * mm;
                if (ln == 0) {
                    float* orow = outBase + (size_t)gi * C;
                    orow[0] = cmx * mm;
                    orow[1] = mA * scj / fmaxf(mA * (float)nv, EPSF);
                }
            }
        }
        __syncthreads();

        // ---- phase 3: channel dots. task -> (row il, channel c in [0,63))
        for (int task = t; task < TI * 63; task += 256) {
            const int il = task / 63, c = task - il * 63;
            float* orow = outBase + (size_t)(i0 + il) * C;
            const float4* a4 = (const float4*)(sa + il * 100);
            if (c < 60) {
                const int grp = c / 20, p = c - grp * 20;
                const float* wrow = (grp == 0 ? w0 : grp == 1 ? w2 : w3) + p * H;
                const float* oth = grp == 0 ? sl : (grp == 1 ? sam : sax) + il * 100;
                const float4* w4 = (const float4*)wrow;
                const float4* o4 = (const float4*)oth;
                float d = 0.f, na = 0.f, nb = 0.f;
                #pragma unroll 5
                for (int k = 0; k < H / 4; ++k) {
                    float4 w = w4[k], a = a4[k], o = o4[k];
                    float ww;
                    ww = w.x * w.x; d += ww * a.x * o.x; na += ww * a.x * a.x; nb += ww * o.x * o.x;
                    ww = w.y * w.y; d += ww * a.y * o.y; na += ww * a.y * a.y; nb += ww * o.y * o.y;
                    ww = w.z * w.z; d += ww * a.z * o.z; na += ww * a.z * a.z; nb += ww * o.z * o.z;
                    ww = w.w * w.w; d += ww * a.w * o.w; na += ww * a.w * a.w; nb += ww * o.w * o.w;
                }
                const int base = (grp == 0) ? 3 : (grp == 1) ? 64 : 85;
                orow[base + p] = d / (fmaxf(sqrtf(na), EPSF) * fmaxf(sqrtf(nb), EPSF));
            } else {
                const float* oth = (c == 60) ? sl : ((c == 61) ? sam : sax) + il * 100;
                const float4* o4 = (const float4*)oth;
                float d = 0.f, na = 0.f, nb = 0.f;
                #pragma unroll 5
                for (int k = 0; k < H / 4; ++k) {
                    float4 a = a4[k], o = o4[k];
                    d += a.x * o.x + a.y * o.y + a.z * o.z + a.w * o.w;
                    na += a.x * a.x + a.y * a.y + a.z * a.z + a.w * a.w;
                    nb += o.x * o.x + o.y * o.y + o.z * o.z + o.w * o.w;
                }
                orow[(c == 60) ? 2 : (c == 61) ? 63 : 84] =
                    d / (fmaxf(sqrtf(na), EPSF) * fmaxf(sqrtf(nb), EPSF));
            }
        }
    }
}

// ---------------------------------------------------------------- launch
extern "C" void kernel_launch(void* const* d_in, const int* in_sizes, int n_in,
                              void* d_out, int out_size, void* d_ws, size_t ws_size,
                              hipStream_t stream)
{
    const float* ctx_p = (const float*)d_in[0];
    const int*   mask_p = (const int*)d_in[1];
    const float* ctx_h = (const float*)d_in[2];
    const int*   mask_h = (const int*)d_in[3];
    const float* w0 = (const float*)d_in[4];
    const float* w1 = (const float*)d_in[5];
    const float* w2 = (const float*)d_in[6];
    const float* w3 = (const float*)d_in[7];
    float* out = (float*)d_out;

    float* ws   = (float*)d_ws;
    float* cp   = ws;                       // B*L*H
    float* ch   = cp   + B * L * H;
    float* np_  = ch   + B * L * H;         // B*L
    float* nh_  = np_  + B * L;
    float* nw1p = nh_  + B * L;             // B*L*P
    float* nw1h = nw1p + B * L * P;
    u16*   cpb  = (u16*)(nw1h + B * L * P); // B*L*128 u16
    u16*   chb  = cpb + B * L * 128;

    k_prep<<<dim3(L, B, 2), dim3(128), 0, stream>>>(
        ctx_p, mask_p, ctx_h, mask_h, w1,
        cp, ch, cpb, chb, np_, nh_, nw1p, nw1h);
    k_main<<<dim3(P + 32, B), dim3(256), 0, stream>>>(
        cp, ch, cpb, chb, np_, nh_, nw1p, nw1h, mask_p, mask_h,
        w0, w1, w2, w3, out);
}

// Round 9
// 124.693 us; speedup vs baseline: 1.8770x; 1.0962x over previous
//
#include <hip/hip_runtime.h>
#include <math.h>

// MatchingLayer (BiMPM-style) — MI355X. Round 9: 512-thread k_main blocks.
// Pair path: 8 waves x 16-row stripes (acc[8]/wave). Side path: 1 row/wave in
// phase 2, 1 col-tile/wave in the cos MFMA, single-pass phase 3.
// B=32, L=128, H=100, P=20, C=105.

namespace {
constexpr int B = 32;
constexpr int L = 128;
constexpr int H = 100;
constexpr int P = 20;
constexpr int C = 105;
constexpr int TI = 8;            // i-rows per side tile
constexpr int SMEM_BYTES = 50176;
constexpr float EPSF = 1e-8f;
constexpr float MINV = -1e7f;
}

typedef unsigned short u16;
typedef unsigned int u32;
typedef short sh8 __attribute__((ext_vector_type(8)));   // 8 bf16 (4 VGPRs)
typedef float f4 __attribute__((ext_vector_type(4)));

__device__ __forceinline__ u16 f2bf(float f) {           // RNE f32->bf16
    u32 u = __float_as_uint(f);
    u += 0x7FFFu + ((u >> 16) & 1u);
    return (u16)(u >> 16);
}
__device__ __forceinline__ float bf2f(u32 h) {
    return __uint_as_float(h << 16);
}

// ---------------------------------------------------------------- k_prep
// grid (L,B,2), block 128. Masked vector (fp32 + bf16 K=128 padded copy),
// plain norm + P w1-weighted norms via 5-lane K-split (105 active lanes).
__global__ void k_prep(const float* __restrict__ ctx_p, const int* __restrict__ mask_p,
                       const float* __restrict__ ctx_h, const int* __restrict__ mask_h,
                       const float* __restrict__ w1,
                       float* __restrict__ cp, float* __restrict__ ch,
                       u16* __restrict__ cpb, u16* __restrict__ chb,
                       float* __restrict__ np_, float* __restrict__ nh_,
                       float* __restrict__ nwp, float* __restrict__ nwh)
{
    const int b = blockIdx.y, i = blockIdx.x, side = blockIdx.z, t = threadIdx.x;
    const float* ctx = side ? ctx_h : ctx_p;
    const int*  mask = side ? mask_h : mask_p;
    float* dst  = side ? ch  : cp;
    u16*   dstb = side ? chb : cpb;
    float* nrm  = side ? nh_ : np_;
    float* nw   = side ? nwh : nwp;

    const int row = b * L + i;
    __shared__ __align__(16) float sv2[H];
    const float m = (float)mask[row];
    float v = 0.f;
    if (t < H) {
        v = ctx[row * H + t] * m;
        dst[row * H + t] = v;
        sv2[t] = v * v;
    }
    dstb[row * 128 + t] = f2bf(v);   // zero pad for t>=H
    __syncthreads();

    const int w = t >> 6, ln = t & 63;
    int g = -1, seg = 0;
    if (w == 0) { if (ln < 60) { g = ln / 5; seg = ln % 5; } }
    else        { if (ln < 45) { g = 12 + ln / 5; seg = ln % 5; } }
    if (g >= 0) {
        const float4* v4 = (const float4*)sv2;
        float acc = 0.f;
        if (g < P) {
            const float4* w4 = (const float4*)(w1 + g * H);
            #pragma unroll
            for (int k = seg * 5; k < seg * 5 + 5; ++k) {
                float4 wv_ = w4[k], s = v4[k];
                acc += wv_.x * wv_.x * s.x + wv_.y * wv_.y * s.y +
                       wv_.z * wv_.z * s.z + wv_.w * wv_.w * s.w;
            }
        } else {
            #pragma unroll
            for (int k = seg * 5; k < seg * 5 + 5; ++k) {
                float4 s = v4[k];
                acc += s.x + s.y + s.z + s.w;
            }
        }
        float a1 = __shfl(acc, ln + 1), a2 = __shfl(acc, ln + 2);
        float a3 = __shfl(acc, ln + 3), a4 = __shfl(acc, ln + 4);
        if (seg == 0) {
            float s = acc + a1 + a2 + a3 + a4;
            if (g < P) nw[row * P + g] = sqrtf(s);
            else       nrm[row] = sqrtf(s);
        }
    }
}

// ---------------------------------------------------------------- k_main
// 512 threads. bx<P: pair GEMM for p=bx. bx>=P: side tile.
__global__ __launch_bounds__(512) void
k_main(const float* __restrict__ cp, const float* __restrict__ ch,
       const u16* __restrict__ cpb, const u16* __restrict__ chb,
       const float* __restrict__ np_, const float* __restrict__ nh_,
       const float* __restrict__ nw1p, const float* __restrict__ nw1h,
       const int* __restrict__ mask_p, const int* __restrict__ mask_h,
       const float* __restrict__ w0, const float* __restrict__ w1,
       const float* __restrict__ w2, const float* __restrict__ w3,
       float* __restrict__ out)
{
    __shared__ __align__(16) char smem[SMEM_BYTES];
    const int bx = blockIdx.x, b = blockIdx.y, t = threadIdx.x;
    const int wv = t >> 6, ln = t & 63;
    float* out_p = out;
    float* out_h = out + (size_t)B * L * C;

    if (bx < P) {
        // ==================== pair path (8 waves x 16-row stripes) ==========
        const int p = bx;
        u16*  sB    = (u16*)smem;                      // [128][136]
        float* snwA = (float*)(smem + 34816);
        float* snwB = (float*)(smem + 35328);
        float* smA  = (float*)(smem + 35840);
        float* smB  = (float*)(smem + 36352);
        float* pJmax= (float*)(smem + 36864);
        float* pJsum= (float*)(smem + 37376);
        float* pImax= (float*)(smem + 37888);          // [8][128]
        float* pIsum= (float*)(smem + 41984);          // [8][128]
        float* sRed = (float*)(smem + 46080);          // 4

        if (t < 128) {
            snwA[t] = nw1p[(b * L + t) * P + p];
            snwB[t] = nw1h[(b * L + t) * P + p];
            smA[t] = (float)mask_p[b * L + t];
            smB[t] = (float)mask_h[b * L + t];
        }
        __syncthreads();

        if (t < 64) {
            float a0 = smB[t], a1 = smB[t + 64];
            float mx = fmaxf(a0, a1), sm = a0 + a1;
            for (int d = 1; d < 64; d <<= 1) {
                mx = fmaxf(mx, __shfl_xor(mx, d));
                sm += __shfl_xor(sm, d);
            }
            if (t == 0) { sRed[2] = mx; sRed[3] = sm; }
        } else if (t < 128) {
            const int l = t - 64;
            float a0 = smA[l], a1 = smA[l + 64];
            float mx = fmaxf(a0, a1), sm = a0 + a1;
            for (int d = 1; d < 64; d <<= 1) {
                mx = fmaxf(mx, __shfl_xor(mx, d));
                sm += __shfl_xor(sm, d);
            }
            if (l == 0) { sRed[0] = mx; sRed[1] = sm; }
        }

        {   // stage B (h-side bf16 rows) into LDS, padded stride 136
            const uint4* src = (const uint4*)(chb + (size_t)b * L * 128);
            #pragma unroll
            for (int it = 0; it < 4; ++it) {
                int idx = it * 512 + t;
                int row = idx >> 4, kc = (idx & 15) * 8;
                uint4 v = src[idx];
                *(uint4*)&sB[row * 136 + kc] = v;
            }
        }
        __syncthreads();

        const int m = ln & 15, q = ln >> 4;

        float swv[4][8];
        #pragma unroll
        for (int ks = 0; ks < 4; ++ks)
            #pragma unroll
            for (int e = 0; e < 8; ++e) {
                int k = ks * 32 + q * 8 + e;
                float w = (k < H) ? w1[p * H + k] : 0.f;
                swv[ks][e] = w * w;
            }

        f4 acc[8];
        #pragma unroll
        for (int ct = 0; ct < 8; ++ct) acc[ct] = (f4){0.f, 0.f, 0.f, 0.f};

        const uint4* gA = (const uint4*)(cpb + (size_t)(b * L + wv * 16 + m) * 128);

        #pragma unroll
        for (int ks = 0; ks < 4; ++ks) {
            uint4 va = gA[ks * 4 + q];
            sh8 af;
            {
                u32 vs[4] = {va.x, va.y, va.z, va.w};
                u32 r[4];
                #pragma unroll
                for (int e = 0; e < 4; ++e) {
                    float f0 = bf2f(vs[e] & 0xffffu) * swv[ks][2 * e];
                    float f1 = bf2f(vs[e] >> 16) * swv[ks][2 * e + 1];
                    r[e] = (u32)f2bf(f0) | ((u32)f2bf(f1) << 16);
                }
                uint4 o = {r[0], r[1], r[2], r[3]};
                af = __builtin_bit_cast(sh8, o);
            }
            const int ko = ks * 32 + q * 8;
            #pragma unroll
            for (int ct = 0; ct < 8; ++ct) {
                sh8 bb = *(const sh8*)&sB[(ct * 16 + m) * 136 + ko];
                acc[ct] = __builtin_amdgcn_mfma_f32_16x16x32_bf16(af, bb, acc[ct], 0, 0, 0);
            }
        }

        // epilogue: mv = acc / max(nwA*nwB, eps); pool over j and i
        float nB[8], mBv[8], imax[8], isum[8];
        #pragma unroll
        for (int ct = 0; ct < 8; ++ct) {
            const int j = ct * 16 + m;
            nB[ct] = snwB[j]; mBv[ct] = smB[j];
            imax[ct] = MINV; isum[ct] = 0.f;
        }
        #pragma unroll
        for (int reg = 0; reg < 4; ++reg) {
            const int i = wv * 16 + q * 4 + reg;
            const float na = snwA[i];
            const float ma = smA[i];
            float jmax = MINV, jsum = 0.f;
            #pragma unroll
            for (int ct = 0; ct < 8; ++ct) {
                float v = acc[ct][reg] *
                          __builtin_amdgcn_rcpf(fmaxf(na * nB[ct], EPSF));
                jmax = fmaxf(jmax, mBv[ct] > 0.f ? v : MINV);
                jsum += mBv[ct] > 0.f ? v : 0.f;
                imax[ct] = fmaxf(imax[ct], ma > 0.f ? v : MINV);
                isum[ct] += ma > 0.f ? v : 0.f;
            }
            for (int d = 1; d < 16; d <<= 1) {
                jmax = fmaxf(jmax, __shfl_xor(jmax, d));
                jsum += __shfl_xor(jsum, d);
            }
            if (m == 0) { pJmax[i] = jmax; pJsum[i] = jsum; }
        }
        #pragma unroll
        for (int ct = 0; ct < 8; ++ct) {
            float mx = imax[ct], sm = isum[ct];
            mx = fmaxf(mx, __shfl_xor(mx, 16)); sm += __shfl_xor(sm, 16);
            mx = fmaxf(mx, __shfl_xor(mx, 32)); sm += __shfl_xor(sm, 32);
            if (q == 0) { const int j = ct * 16 + m; pImax[wv * 128 + j] = mx; pIsum[wv * 128 + j] = sm; }
        }
        __syncthreads();

        if (t < 128) {
            const int i = t;
            const float ma = smA[i];
            const float mm = ma * sRed[2];
            const float cnt = ma * sRed[3];
            float* orow = out_p + ((size_t)b * L + i) * C;
            orow[23 + p] = pJmax[i] * mm;
            orow[43 + p] = ma * pJsum[i] / fmaxf(cnt, EPSF);

            const float mb = smB[i];
            float hmax = MINV, hsum = 0.f;
            #pragma unroll
            for (int s = 0; s < 8; ++s) {
                hmax = fmaxf(hmax, pImax[s * 128 + i]);
                hsum += pIsum[s * 128 + i];
            }
            float* hrow = out_h + ((size_t)b * L + i) * C;
            hrow[23 + p] = hmax * mb * sRed[0];
            hrow[43 + p] = mb * hsum / fmaxf(mb * sRed[1], EPSF);
        }
    } else {
        // ==================== side path ====================
        const int e = bx - P;
        const int side = e >> 4, tile = e & 15;
        const int i0 = tile * TI;
        const float* A   = side ? ch : cp;
        const float* Bv  = side ? cp : ch;
        const u16*  Ab16 = side ? chb : cpb;
        const u16*  Bvb  = side ? cpb : chb;
        const float* nA_ = side ? nh_ : np_;
        const float* nB_ = side ? np_ : nh_;
        const int* maskA = side ? mask_h : mask_p;
        const int* maskB = side ? mask_p : mask_h;
        float* outBase = out + ((size_t)side * B * L + (size_t)b * L) * C;

        float* scosC = (float*)(smem + 34816);
        float* sa    = (float*)(smem + 38912);
        float* sam   = (float*)(smem + 42112);
        float* sax   = (float*)(smem + 45312);
        float* sl    = (float*)(smem + 48512);
        float* snB   = (float*)(smem + 48912);
        u16*  cidx  = (u16*)(smem + 49424);
        float* snA   = (float*)(smem + 49680);
        int*   pnv   = (int*)(smem + 49712);

        // ---- phase 0: valid-j list (wave 0) + A-row fp32 staging (waves 2-7)
        if (wv == 0) {
            int m0 = maskB[b * L + ln], m1 = maskB[b * L + 64 + ln];
            unsigned long long b0 = __ballot(m0 > 0);
            unsigned long long b1 = __ballot(m1 > 0);
            unsigned long long pre = (1ull << ln) - 1ull;
            int n0 = __popcll(b0);
            if (m0 > 0) cidx[__popcll(b0 & pre)] = (u16)ln;
            if (m1 > 0) cidx[n0 + __popcll(b1 & pre)] = (u16)(64 + ln);
            if (ln == 0) *pnv = n0 + __popcll(b1);
        } else if (wv >= 2) {
            for (int x = t - 128; x < TI * 128; x += 384) {
                int il = x >> 7, k = x & 127;
                if (k < H) sa[il * 100 + k] = A[((size_t)b * L + i0 + il) * H + k];
            }
        }
        __syncthreads();
        const int nv = *pnv;
        const int nct = (nv + 15) >> 4;

        // ---- phase 1: compact bf16 Bv rows (stride 272 B, zero tail) +
        //      norms + sl
        {
            const uint4* src = (const uint4*)(Bvb + (size_t)b * L * 128);
            for (int c = t; c < nct * 256; c += 512) {
                int jj = c >> 4, cc = c & 15;
                uint4 v;
                if (jj < nv) v = src[(int)cidx[jj] * 16 + cc];
                else { v.x = v.y = v.z = v.w = 0u; }
                *(uint4*)(smem + jj * 272 + cc * 16) = v;
            }
            if (t < 128) snB[t] = (t < nv) ? nB_[b * L + (int)cidx[t]] : 0.f;
            else if (t < 136) snA[t - 128] = nA_[b * L + i0 + (t - 128)];
            if (wv == 1) {
                int last = nv - 1; if (last < 0) last = 0;
                const float* lr = Bv + ((size_t)b * L + last) * H;
                sl[ln] = lr[ln];
                if (ln + 64 < H) sl[ln + 64] = lr[ln + 64];
            }
        }
        __syncthreads();

        // ---- phase cos: wave wv owns col-tile ct=wv (nct <= 8)
        const int m = ln & 15, q = ln >> 4;
        if (wv < nct) {
            const uint4* gA = (const uint4*)(Ab16 + (size_t)(b * L + i0 + (m & 7)) * 128);
            f4 acc0 = (f4){0.f, 0.f, 0.f, 0.f};
            #pragma unroll
            for (int ks = 0; ks < 4; ++ks) {
                uint4 va = gA[ks * 4 + q];
                if (m >= 8) { va.x = va.y = va.z = va.w = 0u; }
                sh8 af = __builtin_bit_cast(sh8, va);
                const int ko2 = (ks * 32 + q * 8) * 2;
                sh8 bb = *(const sh8*)(smem + (wv * 16 + m) * 272 + ko2);
                acc0 = __builtin_amdgcn_mfma_f32_16x16x32_bf16(af, bb, acc0, 0, 0, 0);
            }
            if (q < 2) {
                #pragma unroll
                for (int reg = 0; reg < 4; ++reg) {
                    const int i = q * 4 + reg;
                    const int jj = wv * 16 + m;
                    scosC[i * 128 + jj] = acc0[reg] *
                        __builtin_amdgcn_rcpf(fmaxf(snA[i] * snB[jj], EPSF));
                }
            }
        }
        __syncthreads();

        // ---- phase 2: wave wv owns row il=wv; lane -> k = {2ln, 2ln+1}
        {
            const int il = wv;
            const int gi = i0 + il;
            if (ln < 50) {
                const float mA = (float)maskA[b * L + gi];
                float am0 = 0.f, am1 = 0.f, ax0 = MINV, ax1 = MINV;
                float scj = 0.f, cmx = MINV;
                const u32* bp = (const u32*)smem + ln;       // row stride 68 dwords
                const float* cr = scosC + il * 128;
                #pragma unroll 4
                for (int jj = 0; jj < nv; ++jj) {
                    u32 pk = bp[jj * 68];
                    float cj = cr[jj];
                    scj += cj; cmx = fmaxf(cmx, cj);
                    float v0 = cj * __uint_as_float(pk << 16);
                    float v1 = cj * __uint_as_float(pk & 0xffff0000u);
                    am0 += v0; am1 += v1;
                    ax0 = fmaxf(ax0, v0); ax1 = fmaxf(ax1, v1);
                }
                const float rs = __builtin_amdgcn_rcpf(fmaxf(scj, EPSF));
                const float mm = (nv > 0) ? mA : 0.f;
                sam[il * 100 + 2 * ln] = am0 * rs; sam[il * 100 + 2 * ln + 1] = am1 * rs;
                sax[il * 100 + 2 * ln] = ax0 * mm; sax[il * 100 + 2 * ln + 1] = ax1 * mm;
                if (ln == 0) {
                    float* orow = outBase + (size_t)gi * C;
                    orow[0] = cmx * mm;
                    orow[1] = mA * scj / fmaxf(mA * (float)nv, EPSF);
                }
            }
        }
        __syncthreads();

        // ---- phase 3: channel dots. task -> (row il, channel c in [0,63))
        for (int task = t; task < TI * 63; task += 512) {
            const int il = task / 63, c = task - il * 63;
            float* orow = outBase + (size_t)(i0 + il) * C;
            const float4* a4 = (const float4*)(sa + il * 100);
            if (c < 60) {
                const int grp = c / 20, p = c - grp * 20;
                const float* wrow = (grp == 0 ? w0 : grp == 1 ? w2 : w3) + p * H;
                const float* oth = grp == 0 ? sl : (grp == 1 ? sam : sax) + il * 100;
                const float4* w4 = (const float4*)wrow;
                const float4* o4 = (const float4*)oth;
                float d = 0.f, na = 0.f, nb = 0.f;
                #pragma unroll 5
                for (int k = 0; k < H / 4; ++k) {
                    float4 w = w4[k], a = a4[k], o = o4[k];
                    float ww;
                    ww = w.x * w.x; d += ww * a.x * o.x; na += ww * a.x * a.x; nb += ww * o.x * o.x;
                    ww = w.y * w.y; d += ww * a.y * o.y; na += ww * a.y * a.y; nb += ww * o.y * o.y;
                    ww = w.z * w.z; d += ww * a.z * o.z; na += ww * a.z * a.z; nb += ww * o.z * o.z;
                    ww = w.w * w.w; d += ww * a.w * o.w; na += ww * a.w * a.w; nb += ww * o.w * o.w;
                }
                const int base = (grp == 0) ? 3 : (grp == 1) ? 64 : 85;
                orow[base + p] = d / (fmaxf(sqrtf(na), EPSF) * fmaxf(sqrtf(nb), EPSF));
            } else {
                const float* oth = (c == 60) ? sl : ((c == 61) ? sam : sax) + il * 100;
                const float4* o4 = (const float4*)oth;
                float d = 0.f, na = 0.f, nb = 0.f;
                #pragma unroll 5
                for (int k = 0; k < H / 4; ++k) {
                    float4 a = a4[k], o = o4[k];
                    d += a.x * o.x + a.y * o.y + a.z * o.z + a.w * o.w;
                    na += a.x * a.x + a.y * a.y + a.z * a.z + a.w * a.w;
                    nb += o.x * o.x + o.y * o.y + o.z * o.z + o.w * o.w;
                }
                orow[(c == 60) ? 2 : (c == 61) ? 63 : 84] =
                    d / (fmaxf(sqrtf(na), EPSF) * fmaxf(sqrtf(nb), EPSF));
            }
        }
    }
}

// ---------------------------------------------------------------- launch
extern "C" void kernel_launch(void* const* d_in, const int* in_sizes, int n_in,
                              void* d_out, int out_size, void* d_ws, size_t ws_size,
                              hipStream_t stream)
{
    const float* ctx_p = (const float*)d_in[0];
    const int*   mask_p = (const int*)d_in[1];
    const float* ctx_h = (const float*)d_in[2];
    const int*   mask_h = (const int*)d_in[3];
    const float* w0 = (const float*)d_in[4];
    const float* w1 = (const float*)d_in[5];
    const float* w2 = (const float*)d_in[6];
    const float* w3 = (const float*)d_in[7];
    float* out = (float*)d_out;

    float* ws   = (float*)d_ws;
    float* cp   = ws;                       // B*L*H
    float* ch   = cp   + B * L * H;
    float* np_  = ch   + B * L * H;         // B*L
    float* nh_  = np_  + B * L;
    float* nw1p = nh_  + B * L;             // B*L*P
    float* nw1h = nw1p + B * L * P;
    u16*   cpb  = (u16*)(nw1h + B * L * P); // B*L*128 u16
    u16*   chb  = cpb + B * L * 128;

    k_prep<<<dim3(L, B, 2), dim3(128), 0, stream>>>(
        ctx_p, mask_p, ctx_h, mask_h, w1,
        cp, ch, cpb, chb, np_, nh_, nw1p, nw1h);
    k_main<<<dim3(P + 32, B), dim3(512), 0, stream>>>(
        cp, ch, cpb, chb, np_, nh_, nw1p, nw1h, mask_p, mask_h,
        w0, w1, w2, w3, out);
}

// Round 10
// 124.038 us; speedup vs baseline: 1.8869x; 1.0053x over previous
//
#include <hip/hip_runtime.h>
#include <math.h>

// MatchingLayer (BiMPM-style) — MI355X. Round 10: side-path phase-3 channel
// dots via MFMA (w^2-stack x product-columns), scj/cmx hoisted to a butterfly.
// Grid (20+32, B) x 512 thr. B=32, L=128, H=100, P=20, C=105.

namespace {
constexpr int B = 32;
constexpr int L = 128;
constexpr int H = 100;
constexpr int P = 20;
constexpr int C = 105;
constexpr int TI = 8;            // i-rows per side tile
constexpr int SMEM_BYTES = 50176;
constexpr float EPSF = 1e-8f;
constexpr float MINV = -1e7f;
}

typedef unsigned short u16;
typedef unsigned int u32;
typedef short sh8 __attribute__((ext_vector_type(8)));   // 8 bf16 (4 VGPRs)
typedef float f4 __attribute__((ext_vector_type(4)));

__device__ __forceinline__ u16 f2bf(float f) {           // RNE f32->bf16
    u32 u = __float_as_uint(f);
    u += 0x7FFFu + ((u >> 16) & 1u);
    return (u16)(u >> 16);
}
__device__ __forceinline__ float bf2f(u32 h) {
    return __uint_as_float(h << 16);
}
__device__ __forceinline__ u32 pack2(float a, float b) {
    return (u32)f2bf(a) | ((u32)f2bf(b) << 16);
}

// ---------------------------------------------------------------- k_prep
__global__ void k_prep(const float* __restrict__ ctx_p, const int* __restrict__ mask_p,
                       const float* __restrict__ ctx_h, const int* __restrict__ mask_h,
                       const float* __restrict__ w1,
                       float* __restrict__ cp, float* __restrict__ ch,
                       u16* __restrict__ cpb, u16* __restrict__ chb,
                       float* __restrict__ np_, float* __restrict__ nh_,
                       float* __restrict__ nwp, float* __restrict__ nwh)
{
    const int b = blockIdx.y, i = blockIdx.x, side = blockIdx.z, t = threadIdx.x;
    const float* ctx = side ? ctx_h : ctx_p;
    const int*  mask = side ? mask_h : mask_p;
    float* dst  = side ? ch  : cp;
    u16*   dstb = side ? chb : cpb;
    float* nrm  = side ? nh_ : np_;
    float* nw   = side ? nwh : nwp;

    const int row = b * L + i;
    __shared__ __align__(16) float sv2[H];
    const float m = (float)mask[row];
    float v = 0.f;
    if (t < H) {
        v = ctx[row * H + t] * m;
        dst[row * H + t] = v;
        sv2[t] = v * v;
    }
    dstb[row * 128 + t] = f2bf(v);   // zero pad for t>=H
    __syncthreads();

    const int w = t >> 6, ln = t & 63;
    int g = -1, seg = 0;
    if (w == 0) { if (ln < 60) { g = ln / 5; seg = ln % 5; } }
    else        { if (ln < 45) { g = 12 + ln / 5; seg = ln % 5; } }
    if (g >= 0) {
        const float4* v4 = (const float4*)sv2;
        float acc = 0.f;
        if (g < P) {
            const float4* w4 = (const float4*)(w1 + g * H);
            #pragma unroll
            for (int k = seg * 5; k < seg * 5 + 5; ++k) {
                float4 wv_ = w4[k], s = v4[k];
                acc += wv_.x * wv_.x * s.x + wv_.y * wv_.y * s.y +
                       wv_.z * wv_.z * s.z + wv_.w * wv_.w * s.w;
            }
        } else {
            #pragma unroll
            for (int k = seg * 5; k < seg * 5 + 5; ++k) {
                float4 s = v4[k];
                acc += s.x + s.y + s.z + s.w;
            }
        }
        float a1 = __shfl(acc, ln + 1), a2 = __shfl(acc, ln + 2);
        float a3 = __shfl(acc, ln + 3), a4 = __shfl(acc, ln + 4);
        if (seg == 0) {
            float s = acc + a1 + a2 + a3 + a4;
            if (g < P) nw[row * P + g] = sqrtf(s);
            else       nrm[row] = sqrtf(s);
        }
    }
}

// ---------------------------------------------------------------- k_main
__global__ __launch_bounds__(512) void
k_main(const float* __restrict__ cp, const float* __restrict__ ch,
       const u16* __restrict__ cpb, const u16* __restrict__ chb,
       const float* __restrict__ np_, const float* __restrict__ nh_,
       const float* __restrict__ nw1p, const float* __restrict__ nw1h,
       const int* __restrict__ mask_p, const int* __restrict__ mask_h,
       const float* __restrict__ w0, const float* __restrict__ w1,
       const float* __restrict__ w2, const float* __restrict__ w3,
       float* __restrict__ out)
{
    __shared__ __align__(16) char smem[SMEM_BYTES];
    const int bx = blockIdx.x, b = blockIdx.y, t = threadIdx.x;
    const int wv = t >> 6, ln = t & 63;
    float* out_p = out;
    float* out_h = out + (size_t)B * L * C;

    if (bx < P) {
        // ==================== pair path (unchanged from R9) ====================
        const int p = bx;
        u16*  sB    = (u16*)smem;                      // [128][136]
        float* snwA = (float*)(smem + 34816);
        float* snwB = (float*)(smem + 35328);
        float* smA  = (float*)(smem + 35840);
        float* smB  = (float*)(smem + 36352);
        float* pJmax= (float*)(smem + 36864);
        float* pJsum= (float*)(smem + 37376);
        float* pImax= (float*)(smem + 37888);          // [8][128]
        float* pIsum= (float*)(smem + 41984);          // [8][128]
        float* sRed = (float*)(smem + 46080);          // 4

        if (t < 128) {
            snwA[t] = nw1p[(b * L + t) * P + p];
            snwB[t] = nw1h[(b * L + t) * P + p];
            smA[t] = (float)mask_p[b * L + t];
            smB[t] = (float)mask_h[b * L + t];
        }
        __syncthreads();

        if (t < 64) {
            float a0 = smB[t], a1 = smB[t + 64];
            float mx = fmaxf(a0, a1), sm = a0 + a1;
            for (int d = 1; d < 64; d <<= 1) {
                mx = fmaxf(mx, __shfl_xor(mx, d));
                sm += __shfl_xor(sm, d);
            }
            if (t == 0) { sRed[2] = mx; sRed[3] = sm; }
        } else if (t < 128) {
            const int l = t - 64;
            float a0 = smA[l], a1 = smA[l + 64];
            float mx = fmaxf(a0, a1), sm = a0 + a1;
            for (int d = 1; d < 64; d <<= 1) {
                mx = fmaxf(mx, __shfl_xor(mx, d));
                sm += __shfl_xor(sm, d);
            }
            if (l == 0) { sRed[0] = mx; sRed[1] = sm; }
        }

        {   // stage B (h-side bf16 rows), padded stride 136
            const uint4* src = (const uint4*)(chb + (size_t)b * L * 128);
            #pragma unroll
            for (int it = 0; it < 4; ++it) {
                int idx = it * 512 + t;
                int row = idx >> 4, kc = (idx & 15) * 8;
                uint4 v = src[idx];
                *(uint4*)&sB[row * 136 + kc] = v;
            }
        }
        __syncthreads();

        const int m = ln & 15, q = ln >> 4;

        float swv[4][8];
        #pragma unroll
        for (int ks = 0; ks < 4; ++ks)
            #pragma unroll
            for (int e = 0; e < 8; ++e) {
                int k = ks * 32 + q * 8 + e;
                float w = (k < H) ? w1[p * H + k] : 0.f;
                swv[ks][e] = w * w;
            }

        f4 acc[8];
        #pragma unroll
        for (int ct = 0; ct < 8; ++ct) acc[ct] = (f4){0.f, 0.f, 0.f, 0.f};

        const uint4* gA = (const uint4*)(cpb + (size_t)(b * L + wv * 16 + m) * 128);

        #pragma unroll
        for (int ks = 0; ks < 4; ++ks) {
            uint4 va = gA[ks * 4 + q];
            sh8 af;
            {
                u32 vs[4] = {va.x, va.y, va.z, va.w};
                u32 r[4];
                #pragma unroll
                for (int e = 0; e < 4; ++e) {
                    float f0 = bf2f(vs[e] & 0xffffu) * swv[ks][2 * e];
                    float f1 = bf2f(vs[e] >> 16) * swv[ks][2 * e + 1];
                    r[e] = (u32)f2bf(f0) | ((u32)f2bf(f1) << 16);
                }
                uint4 o = {r[0], r[1], r[2], r[3]};
                af = __builtin_bit_cast(sh8, o);
            }
            const int ko = ks * 32 + q * 8;
            #pragma unroll
            for (int ct = 0; ct < 8; ++ct) {
                sh8 bb = *(const sh8*)&sB[(ct * 16 + m) * 136 + ko];
                acc[ct] = __builtin_amdgcn_mfma_f32_16x16x32_bf16(af, bb, acc[ct], 0, 0, 0);
            }
        }

        float nB[8], mBv[8], imax[8], isum[8];
        #pragma unroll
        for (int ct = 0; ct < 8; ++ct) {
            const int j = ct * 16 + m;
            nB[ct] = snwB[j]; mBv[ct] = smB[j];
            imax[ct] = MINV; isum[ct] = 0.f;
        }
        #pragma unroll
        for (int reg = 0; reg < 4; ++reg) {
            const int i = wv * 16 + q * 4 + reg;
            const float na = snwA[i];
            const float ma = smA[i];
            float jmax = MINV, jsum = 0.f;
            #pragma unroll
            for (int ct = 0; ct < 8; ++ct) {
                float v = acc[ct][reg] *
                          __builtin_amdgcn_rcpf(fmaxf(na * nB[ct], EPSF));
                jmax = fmaxf(jmax, mBv[ct] > 0.f ? v : MINV);
                jsum += mBv[ct] > 0.f ? v : 0.f;
                imax[ct] = fmaxf(imax[ct], ma > 0.f ? v : MINV);
                isum[ct] += ma > 0.f ? v : 0.f;
            }
            for (int d = 1; d < 16; d <<= 1) {
                jmax = fmaxf(jmax, __shfl_xor(jmax, d));
                jsum += __shfl_xor(jsum, d);
            }
            if (m == 0) { pJmax[i] = jmax; pJsum[i] = jsum; }
        }
        #pragma unroll
        for (int ct = 0; ct < 8; ++ct) {
            float mx = imax[ct], sm = isum[ct];
            mx = fmaxf(mx, __shfl_xor(mx, 16)); sm += __shfl_xor(sm, 16);
            mx = fmaxf(mx, __shfl_xor(mx, 32)); sm += __shfl_xor(sm, 32);
            if (q == 0) { const int j = ct * 16 + m; pImax[wv * 128 + j] = mx; pIsum[wv * 128 + j] = sm; }
        }
        __syncthreads();

        if (t < 128) {
            const int i = t;
            const float ma = smA[i];
            const float mm = ma * sRed[2];
            const float cnt = ma * sRed[3];
            float* orow = out_p + ((size_t)b * L + i) * C;
            orow[23 + p] = pJmax[i] * mm;
            orow[43 + p] = ma * pJsum[i] / fmaxf(cnt, EPSF);

            const float mb = smB[i];
            float hmax = MINV, hsum = 0.f;
            #pragma unroll
            for (int s = 0; s < 8; ++s) {
                hmax = fmaxf(hmax, pImax[s * 128 + i]);
                hsum += pIsum[s * 128 + i];
            }
            float* hrow = out_h + ((size_t)b * L + i) * C;
            hrow[23 + p] = hmax * mb * sRed[0];
            hrow[43 + p] = mb * hsum / fmaxf(mb * sRed[1], EPSF);
        }
    } else {
        // ==================== side path ====================
        // LDS map (bytes):
        //   0     : BvC compact [<=128][272]          (phases 1-2)
        //           overlay A (post phase-2): Bcols [8][8][136]u16 @0 (17408),
        //                                     w2sq  [64][136]u16  @17408 (17408)
        //           overlay B (post MFMA):    Dscr  [8][64][8]f32 @0 (16384)
        //   34816 : scosC [8][128] f32 (zero-init)
        //   38912 : sa  [8][112] f32
        //   42496 : sam [8][112] f32   (pre-phase2 overlay: snB@42496 [128]f32,
        //                               snA@43008 [8]f32, cidx@43040 [128]u16)
        //   46080 : sax [8][112] f32
        //   49664 : sl  [112] f32
        //   50112 : nv  int
        const int e = bx - P;
        const int side = e >> 4, tile = e & 15;
        const int i0 = tile * TI;
        const float* A   = side ? ch : cp;
        const float* Bv  = side ? cp : ch;
        const u16*  Ab16 = side ? chb : cpb;
        const u16*  Bvb  = side ? cpb : chb;
        const float* nA_ = side ? nh_ : np_;
        const float* nB_ = side ? np_ : nh_;
        const int* maskA = side ? mask_h : mask_p;
        const int* maskB = side ? mask_p : mask_h;
        float* outBase = out + ((size_t)side * B * L + (size_t)b * L) * C;

        float* scosC = (float*)(smem + 34816);
        float* sa    = (float*)(smem + 38912);
        float* sam   = (float*)(smem + 42496);
        float* sax   = (float*)(smem + 46080);
        float* sl    = (float*)(smem + 49664);
        float* snB   = (float*)(smem + 42496);
        float* snA   = (float*)(smem + 43008);
        u16*  cidx  = (u16*)(smem + 43040);
        int*   pnv   = (int*)(smem + 50112);

        // ---- phase 0: zero scosC; valid-j list (wave 0); A rows (waves 2-7)
        scosC[t] = 0.f;
        scosC[t + 512] = 0.f;
        if (wv == 0) {
            int m0 = maskB[b * L + ln], m1 = maskB[b * L + 64 + ln];
            unsigned long long b0 = __ballot(m0 > 0);
            unsigned long long b1 = __ballot(m1 > 0);
            unsigned long long pre = (1ull << ln) - 1ull;
            int n0 = __popcll(b0);
            if (m0 > 0) cidx[__popcll(b0 & pre)] = (u16)ln;
            if (m1 > 0) cidx[n0 + __popcll(b1 & pre)] = (u16)(64 + ln);
            if (ln == 0) *pnv = n0 + __popcll(b1);
        } else if (wv >= 2) {
            for (int x = t - 128; x < TI * 128; x += 384) {
                int il = x >> 7, k = x & 127;
                if (k < H) sa[il * 112 + k] = A[((size_t)b * L + i0 + il) * H + k];
            }
        }
        __syncthreads();
        const int nv = *pnv;
        const int nct = (nv + 15) >> 4;

        // ---- phase 1: compact bf16 Bv rows (stride 272 B, zero tail) + norms + sl
        {
            const uint4* src = (const uint4*)(Bvb + (size_t)b * L * 128);
            for (int c = t; c < nct * 256; c += 512) {
                int jj = c >> 4, cc = c & 15;
                uint4 v;
                if (jj < nv) v = src[(int)cidx[jj] * 16 + cc];
                else { v.x = v.y = v.z = v.w = 0u; }
                *(uint4*)(smem + jj * 272 + cc * 16) = v;
            }
            if (t < 128) snB[t] = (t < nv) ? nB_[b * L + (int)cidx[t]] : 0.f;
            else if (t < 136) snA[t - 128] = nA_[b * L + i0 + (t - 128)];
            if (wv == 1) {
                int last = nv - 1; if (last < 0) last = 0;
                const float* lr = Bv + ((size_t)b * L + last) * H;
                sl[ln] = lr[ln];
                if (ln + 64 < H) sl[ln + 64] = lr[ln + 64];
            }
        }
        __syncthreads();

        // ---- phase cos: wave wv owns col-tile ct=wv (nct <= 8)
        const int m = ln & 15, q = ln >> 4;
        if (wv < nct) {
            const uint4* gA = (const uint4*)(Ab16 + (size_t)(b * L + i0 + (m & 7)) * 128);
            f4 acc0 = (f4){0.f, 0.f, 0.f, 0.f};
            #pragma unroll
            for (int ks = 0; ks < 4; ++ks) {
                uint4 va = gA[ks * 4 + q];
                if (m >= 8) { va.x = va.y = va.z = va.w = 0u; }
                sh8 af = __builtin_bit_cast(sh8, va);
                const int ko2 = (ks * 32 + q * 8) * 2;
                sh8 bb = *(const sh8*)(smem + (wv * 16 + m) * 272 + ko2);
                acc0 = __builtin_amdgcn_mfma_f32_16x16x32_bf16(af, bb, acc0, 0, 0, 0);
            }
            if (q < 2) {
                #pragma unroll
                for (int reg = 0; reg < 4; ++reg) {
                    const int i = q * 4 + reg;
                    const int jj = wv * 16 + m;
                    scosC[i * 128 + jj] = acc0[reg] *
                        __builtin_amdgcn_rcpf(fmaxf(snA[i] * snB[jj], EPSF));
                }
            }
        }
        __syncthreads();

        // ---- phase 2: butterfly scalars + attentive am/ax; wave wv = row wv
        {
            const int il = wv;
            const int gi = i0 + il;
            const float mA = (float)maskA[b * L + gi];
            float c0 = scosC[il * 128 + ln], c1 = scosC[il * 128 + 64 + ln];
            float scj = c0 + c1;                 // tail zeros contribute 0
            float mv0 = (ln < nv) ? c0 : MINV;
            float mv1 = (ln + 64 < nv) ? c1 : MINV;
            float cmx = fmaxf(mv0, mv1);
            for (int d = 1; d < 64; d <<= 1) {
                scj += __shfl_xor(scj, d);
                cmx = fmaxf(cmx, __shfl_xor(cmx, d));
            }
            const float mm = (nv > 0) ? mA : 0.f;
            if (ln == 0) {
                float* orow = outBase + (size_t)gi * C;
                orow[0] = cmx * mm;
                orow[1] = mA * scj / fmaxf(mA * (float)nv, EPSF);
            }
            if (ln < 50) {
                float am0 = 0.f, am1 = 0.f, ax0 = MINV, ax1 = MINV;
                const u32* bp = (const u32*)smem + ln;       // row stride 68 dwords
                const float* cr = scosC + il * 128;
                #pragma unroll 4
                for (int jj = 0; jj < nv; ++jj) {
                    u32 pk = bp[jj * 68];
                    float cj = cr[jj];
                    float v0 = cj * __uint_as_float(pk << 16);
                    float v1 = cj * __uint_as_float(pk & 0xffff0000u);
                    am0 += v0; am1 += v1;
                    ax0 = fmaxf(ax0, v0); ax1 = fmaxf(ax1, v1);
                }
                const float rs = __builtin_amdgcn_rcpf(fmaxf(scj, EPSF));
                sam[il * 112 + 2 * ln] = am0 * rs; sam[il * 112 + 2 * ln + 1] = am1 * rs;
                sax[il * 112 + 2 * ln] = ax0 * mm; sax[il * 112 + 2 * ln + 1] = ax1 * mm;
            }
        }
        __syncthreads();

        // ---- phase 3a: build Bcols (products, bf16) + w2sq stack (bf16)
        for (int idx = t; idx < 8 * 8 * 17; idx += 512) {
            int kc = (idx % 17) * 8;
            int tmp = idx / 17;                  // il*8 + col
            int il = tmp >> 3, col = tmp & 7;
            const float* sa_il  = sa  + il * 112;
            const float* sam_il = sam + il * 112;
            const float* sax_il = sax + il * 112;
            const float* p1 = (col >= 4) ? (col == 4 ? sl : col == 5 ? sam_il : sax_il)
                                         : sa_il;
            const float* p2 = (col == 0 || col == 4) ? sl :
                              (col == 1 || col == 5) ? sam_il :
                              (col == 2 || col == 6) ? sax_il : sa_il;
            u32 ow[4];
            #pragma unroll
            for (int e2 = 0; e2 < 4; ++e2) {
                int k0 = kc + 2 * e2;
                float f0 = (col < 7 && k0 < H)     ? p1[k0] * p2[k0]         : 0.f;
                float f1 = (col < 7 && k0 + 1 < H) ? p1[k0 + 1] * p2[k0 + 1] : 0.f;
                ow[e2] = pack2(f0, f1);
            }
            uint4 o = {ow[0], ow[1], ow[2], ow[3]};
            *(uint4*)(smem + (tmp * 136 + kc) * 2) = o;
        }
        for (int idx = t; idx < 64 * 17; idx += 512) {
            int kc = (idx % 17) * 8;
            int row = idx / 17;
            u32 ow[4];
            #pragma unroll
            for (int e2 = 0; e2 < 4; ++e2) {
                int k0 = kc + 2 * e2;
                float f0 = 0.f, f1 = 0.f;
                if (row < 60) {
                    const float* wr = (row < 20) ? w0 + row * H :
                                      (row < 40) ? w2 + (row - 20) * H :
                                                   w3 + (row - 40) * H;
                    if (k0 < H)     { float w = wr[k0];     f0 = w * w; }
                    if (k0 + 1 < H) { float w = wr[k0 + 1]; f1 = w * w; }
                } else if (row == 60) {
                    f0 = (k0 < H) ? 1.f : 0.f;
                    f1 = (k0 + 1 < H) ? 1.f : 0.f;
                }
                ow[e2] = pack2(f0, f1);
            }
            uint4 o = {ow[0], ow[1], ow[2], ow[3]};
            *(uint4*)(smem + 17408 + (row * 136 + kc) * 2) = o;
        }
        __syncthreads();

        // ---- phase 3b: D[61x7] = w2sq x Bcols^T per il (wave wv -> il=wv)
        f4 d3[4];
        #pragma unroll
        for (int Mt = 0; Mt < 4; ++Mt) d3[Mt] = (f4){0.f, 0.f, 0.f, 0.f};
        {
            const int cn = m & 7;
            #pragma unroll
            for (int ks = 0; ks < 4; ++ks) {
                const int ko2 = (ks * 32 + q * 8) * 2;
                sh8 bb = *(const sh8*)(smem + ((wv * 8 + cn) * 136) * 2 + ko2);
                #pragma unroll
                for (int Mt = 0; Mt < 4; ++Mt) {
                    sh8 aa = *(const sh8*)(smem + 17408 + ((Mt * 16 + m) * 136) * 2 + ko2);
                    d3[Mt] = __builtin_amdgcn_mfma_f32_16x16x32_bf16(aa, bb, d3[Mt], 0, 0, 0);
                }
            }
        }
        __syncthreads();   // all MFMA reads done before Dscr overwrites

        if (m < 8) {
            #pragma unroll
            for (int Mt = 0; Mt < 4; ++Mt)
                #pragma unroll
                for (int reg = 0; reg < 4; ++reg)
                    ((float*)smem)[wv * 512 + (Mt * 16 + q * 4 + reg) * 8 + m] = d3[Mt][reg];
        }
        __syncthreads();

        // ---- phase 3c: 504 output channels from Dscr
        for (int task = t; task < TI * 63; task += 512) {
            const int il = task / 63, c = task - il * 63;
            int row, dcol, nbcol, chn;
            if (c < 60) {
                const int grp = c / 20;
                row = c; dcol = grp; nbcol = 4 + grp;
                chn = ((grp == 0) ? 3 : (grp == 1) ? 64 : 85) + (c - grp * 20);
            } else {
                const int cc = c - 60;
                row = 60; dcol = cc; nbcol = 4 + cc;
                chn = (cc == 0) ? 2 : (cc == 1) ? 63 : 84;
            }
            const float* Dr = (const float*)smem + il * 512 + row * 8;
            float d = Dr[dcol], na = Dr[3], nb = Dr[nbcol];
            outBase[(size_t)(i0 + il) * C + chn] =
                d / (fmaxf(sqrtf(na), EPSF) * fmaxf(sqrtf(nb), EPSF));
        }
    }
}

// ---------------------------------------------------------------- launch
extern "C" void kernel_launch(void* const* d_in, const int* in_sizes, int n_in,
                              void* d_out, int out_size, void* d_ws, size_t ws_size,
                              hipStream_t stream)
{
    const float* ctx_p = (const float*)d_in[0];
    const int*   mask_p = (const int*)d_in[1];
    const float* ctx_h = (const float*)d_in[2];
    const int*   mask_h = (const int*)d_in[3];
    const float* w0 = (const float*)d_in[4];
    const float* w1 = (const float*)d_in[5];
    const float* w2 = (const float*)d_in[6];
    const float* w3 = (const float*)d_in[7];
    float* out = (float*)d_out;

    float* ws   = (float*)d_ws;
    float* cp   = ws;                       // B*L*H
    float* ch   = cp   + B * L * H;
    float* np_  = ch   + B * L * H;         // B*L
    float* nh_  = np_  + B * L;
    float* nw1p = nh_  + B * L;             // B*L*P
    float* nw1h = nw1p + B * L * P;
    u16*   cpb  = (u16*)(nw1h + B * L * P); // B*L*128 u16
    u16*   chb  = cpb + B * L * 128;

    k_prep<<<dim3(L, B, 2), dim3(128), 0, stream>>>(
        ctx_p, mask_p, ctx_h, mask_h, w1,
        cp, ch, cpb, chb, np_, nh_, nw1p, nw1h);
    k_main<<<dim3(P + 32, B), dim3(512), 0, stream>>>(
        cp, ch, cpb, chb, np_, nh_, nw1p, nw1h, mask_p, mask_h,
        w0, w1, w2, w3, out);
}